// Round 4
// baseline (1881.913 us; speedup 1.0000x reference)
//
#include <hip/hip_runtime.h>
#include <hip/hip_bf16.h>
#include <hip/hip_fp16.h>

// ---------------------------------------------------------------------------
// BiLSTM (N=512, D_IN=300, H=256) + pairwise 3-layer MLP (4H->H->H->50)
// + log_softmax, on MI355X.
//
//   prep   : transposes (WihT, W1aT/W1bT), f16 casts (W2h, W3h pad)
//   xb     : xb[dir][t][4H] = x[t] @ Wih^T + (bih+bhh)
//   lstm   : ONE workgroup per direction, 1024 threads. thread=(gate,unit),
//            whole Whh row in 128 f16x2 VGPRs (no AGPR, no weight LDS).
//            Own-gate activation then 4-lane ds_bpermute all-gather; c,h
//            computed redundantly per quad. Double-buffered h, 1 barrier/step.
//   ab     : a'[i] = out[i]@W1a^T + b1 ; b[j] = out[j]@W1b^T
//   mlp    : fused h1->h2->logits->log_softmax with MFMA 32x32x16 f16
// ---------------------------------------------------------------------------

typedef _Float16 f16x2 __attribute__((ext_vector_type(2)));
typedef _Float16 f16x8 __attribute__((ext_vector_type(8)));
typedef float    f32x16 __attribute__((ext_vector_type(16)));

__device__ __forceinline__ float sigf(float x){ return 1.f/(1.f + __expf(-x)); }
// Packed dot: v_dot2_f32_f16 (f16 mul, f32 accumulate).
__device__ __forceinline__ float dot2f(f16x2 a, f16x2 b, float c){
  float d;
  asm("v_dot2_f32_f16 %0, %1, %2, %3" : "=v"(d) : "v"(a), "v"(b), "v"(c));
  return d;
}

// ------------------------------ prep ---------------------------------------
__global__ __launch_bounds__(256) void prep_kernel(
    const float* __restrict__ Wih_f, const float* __restrict__ Wih_b,
    const float* __restrict__ W1,    const float* __restrict__ W2,
    const float* __restrict__ W3,    const float* __restrict__ b3,
    float* __restrict__ WihT, float* __restrict__ W1aT, float* __restrict__ W1bT,
    _Float16* __restrict__ W2h, _Float16* __restrict__ W3h,
    float* __restrict__ b3p)
{
  int idx = blockIdx.x * 256 + threadIdx.x;
  if (idx < 614400){                     // WihT[d][c][r] = Wih_d[r][c]
    int d = idx / 307200, r2 = idx % 307200;
    int cc = r2 / 1024, rr = r2 % 1024;
    const float* src = d ? Wih_b : Wih_f;
    WihT[idx] = src[rr*300 + cc];
    return;
  }
  idx -= 614400;
  if (idx < 262144){                     // W1aT[c][p]=W1[p][c]; W1bT[c][p]=W1[p][512+c]
    int sel = idx / 131072, r2 = idx % 131072;
    int cc = r2 / 256, pp = r2 % 256;
    float v = W1[pp*1024 + sel*512 + cc];
    (sel ? W1bT : W1aT)[r2] = v;
    return;
  }
  idx -= 262144;
  if (idx < 65536){ W2h[idx] = (_Float16)W2[idx]; return; }
  idx -= 65536;
  if (idx < 16384){                      // W3h padded to [64][256]
    int n = idx >> 8, k = idx & 255;
    W3h[idx] = (n < 50) ? (_Float16)W3[n*256 + k] : (_Float16)0.f;
    return;
  }
  idx -= 16384;
  if (idx < 64){ b3p[idx] = (idx < 50) ? b3[idx] : 0.f; return; }
}

// ------------------------------ xb ------------------------------------------
__global__ __launch_bounds__(256) void xb_kernel(
    const float* __restrict__ x, const float* __restrict__ WihT,
    const float* __restrict__ bih_f, const float* __restrict__ bhh_f,
    const float* __restrict__ bih_b, const float* __restrict__ bhh_b,
    float* __restrict__ xb)
{
  const int tid = threadIdx.x;
  const int dir = blockIdx.x >> 7;
  const int t0  = (blockIdx.x & 127) * 4;
  __shared__ float xs[4][304];
  #pragma unroll
  for (int tt = 0; tt < 4; ++tt)
    if (tid < 75) ((float4*)xs[tt])[tid] = ((const float4*)(x + (size_t)(t0+tt)*300))[tid];
  __syncthreads();
  const float* W = WihT + dir*307200;
  float acc[4][4];
  #pragma unroll
  for (int r = 0; r < 4; ++r){
    #pragma unroll
    for (int tt = 0; tt < 4; ++tt) acc[r][tt] = 0.f;
  }
  for (int c = 0; c < 300; ++c){
    float x0 = xs[0][c], x1 = xs[1][c], x2 = xs[2][c], x3 = xs[3][c];
    #pragma unroll
    for (int r = 0; r < 4; ++r){
      float wv = W[c*1024 + r*256 + tid];
      acc[r][0] += wv*x0; acc[r][1] += wv*x1; acc[r][2] += wv*x2; acc[r][3] += wv*x3;
    }
  }
  const float* bih = dir ? bih_b : bih_f;
  const float* bhh = dir ? bhh_b : bhh_f;
  float* xbd = xb + (size_t)dir*512*1024;
  #pragma unroll
  for (int r = 0; r < 4; ++r){
    int R = r*256 + tid;
    float bias = bih[R] + bhh[R];
    #pragma unroll
    for (int tt = 0; tt < 4; ++tt)
      xbd[(size_t)(t0+tt)*1024 + R] = acc[r][tt] + bias;
  }
}

// ------------------------------ lstm ----------------------------------------
// One block per direction, 1024 threads. Thread t: gate g=t&3, unit j=t>>2,
// owns Whh row g*256+j fully in registers (128 f16x2 = 128 VGPRs).
// Per step: dot(w, h) -> own-gate activation (tanh via 2*sig(2x)-1) ->
// 4-lane bpermute all-gather -> redundant c,h in each quad lane ->
// lane g==0 writes h (f16 LDS double buffer + f32 global). 1 barrier/step.
__global__ __launch_bounds__(1024) void lstm_kernel(
    const float* __restrict__ Whh_f, const float* __restrict__ Whh_b,
    const float* __restrict__ xb, float* __restrict__ outcat)
{
  __shared__ _Float16 hbuf[2][256];
  const int tid = threadIdx.x;
  const int dir = blockIdx.x;
  const int g   = tid & 3;
  const int j   = tid >> 2;
  const int row = g*256 + j;
  const float* Whh = dir ? Whh_b : Whh_f;

  // ---- whole row register-resident: 128 f16x2
  f16x2 w[128];
  {
    const float4* wp = (const float4*)(Whh + (size_t)row*256);
    #pragma unroll
    for (int q = 0; q < 64; ++q){
      float4 v = wp[q];
      f16x2 t0, t1;
      t0[0]=(_Float16)v.x; t0[1]=(_Float16)v.y;
      t1[0]=(_Float16)v.z; t1[1]=(_Float16)v.w;
      w[2*q] = t0; w[2*q+1] = t1;
    }
  }
  // per-lane activation constants: gate 2 (cell) uses tanh = 2*sig(2x)-1
  const float sx = (g==2) ? 2.f : 1.f;
  const float m2 = (g==2) ? 2.f : 1.f;
  const float m3 = (g==2) ? -1.f : 0.f;
  // quad all-gather bpermute byte-addresses (lane index within wave * 4)
  const int qb = ((tid & 63) & ~3) * 4;

  if (tid < 128) ((f16x2*)hbuf[0])[tid] = (f16x2)(_Float16)0.f;  // h_{-1}=0

  const float* xbd = xb + (size_t)dir*512*1024;
  float cst = 0.f;
  int p = 0;
  float xv = xbd[(size_t)(dir ? 511 : 0)*1024 + row];

  for (int it = 0; it < 512; ++it){
    const int t = dir ? (511 - it) : it;
    __syncthreads();                       // h of prev step visible
    float xn = 0.f;
    if (it < 511){                         // prefetch next step's xb
      const int tn = dir ? (510 - it) : (it + 1);
      xn = xbd[(size_t)tn*1024 + row];
    }
    const f16x8* hb = (const f16x8*)hbuf[p];
    float a0=0.f, a1=0.f, a2=0.f, a3=0.f;
    #pragma unroll
    for (int cc = 0; cc < 32; ++cc){
      f16x8 hv = hb[cc];                   // wave-uniform -> broadcast read
      a0 = dot2f(w[4*cc+0], __builtin_shufflevector(hv, hv, 0, 1), a0);
      a1 = dot2f(w[4*cc+1], __builtin_shufflevector(hv, hv, 2, 3), a1);
      a2 = dot2f(w[4*cc+2], __builtin_shufflevector(hv, hv, 4, 5), a2);
      a3 = dot2f(w[4*cc+3], __builtin_shufflevector(hv, hv, 6, 7), a3);
    }
    const float gv = (a0 + a1) + (a2 + a3) + xv;
    const float act = fmaf(sigf(sx * gv), m2, m3);   // own gate activated
    const int ai = __float_as_int(act);
    const float vi = __int_as_float(__builtin_amdgcn_ds_bpermute(qb,      ai));
    const float vf = __int_as_float(__builtin_amdgcn_ds_bpermute(qb + 4,  ai));
    const float vg = __int_as_float(__builtin_amdgcn_ds_bpermute(qb + 8,  ai));
    const float vo = __int_as_float(__builtin_amdgcn_ds_bpermute(qb + 12, ai));
    cst = fmaf(vf, cst, vi * vg);                    // redundant per quad
    const float th = fmaf(sigf(2.f * cst), 2.f, -1.f);
    const float h = vo * th;
    if (g == 0){
      hbuf[p ^ 1][j] = (_Float16)h;
      outcat[(size_t)t*512 + dir*256 + j] = h;
    }
    p ^= 1;
    xv = xn;
  }
}

// ------------------------------ ab ------------------------------------------
__global__ __launch_bounds__(512) void ab_kernel(
    const float* __restrict__ outcat, const float* __restrict__ W1aT,
    const float* __restrict__ W1bT,  const float* __restrict__ b1,
    float* __restrict__ aP, float* __restrict__ bP)
{
  __shared__ float orow[512];
  const int tid = threadIdx.x;
  const int i = blockIdx.x;
  if (tid < 128) ((float4*)orow)[tid] = ((const float4*)(outcat + (size_t)i*512))[tid];
  __syncthreads();
  const int p = tid & 255, sel = tid >> 8;
  const float* W = sel ? W1bT : W1aT;
  float acc = sel ? 0.f : b1[p];
  #pragma unroll 8
  for (int cc = 0; cc < 512; ++cc) acc += orow[cc] * W[cc*256 + p];
  (sel ? bP : aP)[(size_t)i*256 + p] = acc;
}

// ------------------------------ fused MLP -----------------------------------
__global__ __launch_bounds__(256, 2) void mlp_kernel(
    const float* __restrict__ aP, const float* __restrict__ bP,
    const _Float16* __restrict__ W2h, const _Float16* __restrict__ W3h,
    const float* __restrict__ b2, const float* __restrict__ b3p,
    float* __restrict__ outp)
{
  __shared__ _Float16 lds[32768];   // 64KB union: W2 quarter (32KB) / h2 (64KB)
  const int tid = threadIdx.x;
  const int wv  = tid >> 6;
  const int ln  = tid & 31;
  const int hi  = (tid >> 5) & 1;
  const int i     = blockIdx.x >> 2;
  const int jbase = (blockIdx.x & 3) * 128;
  const int j     = jbase + wv*32 + ln;

  f32x16 acc[8];
  #pragma unroll
  for (int nt = 0; nt < 8; ++nt){
    #pragma unroll
    for (int e = 0; e < 16; ++e) acc[nt][e] = 0.f;
  }

  const float* arow = aP + (size_t)i*256;
  const float* brow = bP + (size_t)j*256;

  for (int p = 0; p < 4; ++p){
    if (p) __syncthreads();
    { // stage W2 quarter: rows n=tid, 64 k's, st_16x32 XOR swizzle
      const _Float16* src = W2h + tid*256 + p*64;
      char* dst = (char*)lds + tid*128;
      const int sw = (tid & 7) << 4;
      #pragma unroll
      for (int cc = 0; cc < 8; ++cc){
        f16x8 v = *(const f16x8*)(src + cc*8);
        *(f16x8*)(dst + ((cc*16) ^ sw)) = v;
      }
    }
    __syncthreads();
    #pragma unroll
    for (int ktl = 0; ktl < 4; ++ktl){
      const int kg = (p*4 + ktl)*16 + hi*8;
      float4 a0 = *(const float4*)(arow + kg);
      float4 a1 = *(const float4*)(arow + kg + 4);
      float4 b0 = *(const float4*)(brow + kg);
      float4 b1v = *(const float4*)(brow + kg + 4);
      f16x8 af;
      af[0] = (_Float16)fmaxf(a0.x + b0.x, 0.f);
      af[1] = (_Float16)fmaxf(a0.y + b0.y, 0.f);
      af[2] = (_Float16)fmaxf(a0.z + b0.z, 0.f);
      af[3] = (_Float16)fmaxf(a0.w + b0.w, 0.f);
      af[4] = (_Float16)fmaxf(a1.x + b1v.x, 0.f);
      af[5] = (_Float16)fmaxf(a1.y + b1v.y, 0.f);
      af[6] = (_Float16)fmaxf(a1.z + b1v.z, 0.f);
      af[7] = (_Float16)fmaxf(a1.w + b1v.w, 0.f);
      const int kl2 = (ktl*16 + hi*8) * 2;
      #pragma unroll
      for (int nt = 0; nt < 8; ++nt){
        const int n = nt*32 + ln;
        f16x8 bf = *(const f16x8*)((char*)lds + n*128 + (kl2 ^ ((n & 7) << 4)));
        acc[nt] = __builtin_amdgcn_mfma_f32_32x32x16_f16(af, bf, acc[nt], 0, 0, 0);
      }
    }
  }
  __syncthreads();
  // h2 -> LDS [128 pairs][256 ch] f16, XOR-swizzled per pair-row
  #pragma unroll
  for (int nt = 0; nt < 8; ++nt){
    const int ch = nt*32 + ln;
    const float bb = b2[ch];
    #pragma unroll
    for (int r = 0; r < 16; ++r){
      const int pr = wv*32 + (r & 3) + 8*(r >> 2) + 4*hi;
      const float v = fmaxf(acc[nt][r] + bb, 0.f);
      *(_Float16*)((char*)lds + pr*512 + ((ch*2) ^ ((pr & 7) << 4))) = (_Float16)v;
    }
  }
  __syncthreads();
  // logits
  f32x16 acc2[2];
  #pragma unroll
  for (int nt = 0; nt < 2; ++nt){
    #pragma unroll
    for (int e = 0; e < 16; ++e) acc2[nt][e] = 0.f;
  }
  const int pr = wv*32 + ln;
  const int sw2 = (pr & 7) << 4;
  #pragma unroll
  for (int kt = 0; kt < 16; ++kt){
    const int kb = kt*16 + hi*8;
    f16x8 a2 = *(const f16x8*)((char*)lds + pr*512 + ((kb*2) ^ sw2));
    #pragma unroll
    for (int nt = 0; nt < 2; ++nt){
      const int n = nt*32 + ln;
      f16x8 bf = *(const f16x8*)(W3h + n*256 + kb);
      acc2[nt] = __builtin_amdgcn_mfma_f32_32x32x16_f16(a2, bf, acc2[nt], 0, 0, 0);
    }
  }
  // log_softmax over 50 classes
  const float b30 = b3p[ln], b31 = b3p[32 + ln];
  const bool ok2 = (ln < 18);
  #pragma unroll
  for (int qr = 0; qr < 16; ++qr){
    const int r = (qr & 3) + 8*(qr >> 2) + 4*hi;
    float v0 = acc2[0][qr] + b30;
    float v1 = acc2[1][qr] + b31;
    float m = ok2 ? fmaxf(v0, v1) : v0;
    #pragma unroll
    for (int d = 1; d < 32; d <<= 1) m = fmaxf(m, __shfl_xor(m, d));
    float s = __expf(v0 - m) + (ok2 ? __expf(v1 - m) : 0.f);
    #pragma unroll
    for (int d = 1; d < 32; d <<= 1) s += __shfl_xor(s, d);
    const float lse = m + __logf(s);
    const size_t base = ((size_t)(i*512 + jbase + wv*32 + r)) * 50;
    outp[base + ln] = v0 - lse;
    if (ok2) outp[base + 32 + ln] = v1 - lse;
  }
}

// ------------------------------ launch --------------------------------------
extern "C" void kernel_launch(void* const* d_in, const int* in_sizes, int n_in,
                              void* d_out, int out_size, void* d_ws, size_t ws_size,
                              hipStream_t stream)
{
  const float* x     = (const float*)d_in[0];
  const float* Wih_f = (const float*)d_in[1];
  const float* Whh_f = (const float*)d_in[2];
  const float* bih_f = (const float*)d_in[3];
  const float* bhh_f = (const float*)d_in[4];
  const float* Wih_b = (const float*)d_in[5];
  const float* Whh_b = (const float*)d_in[6];
  const float* bih_b = (const float*)d_in[7];
  const float* bhh_b = (const float*)d_in[8];
  const float* W1    = (const float*)d_in[9];
  const float* b1    = (const float*)d_in[10];
  const float* W2    = (const float*)d_in[11];
  const float* b2    = (const float*)d_in[12];
  const float* W3    = (const float*)d_in[13];
  const float* b3    = (const float*)d_in[14];

  char* ws = (char*)d_ws;
  float*    xb     = (float*)(ws + 0);            // 4,194,304
  float*    outcat = (float*)(ws + 4194304);      // 1,048,576
  float*    aP     = (float*)(ws + 5242880);      //   524,288
  float*    bP     = (float*)(ws + 5767168);      //   524,288
  float*    WihT   = (float*)(ws + 6291456);      // 2,457,600
  float*    W1aT   = (float*)(ws + 8749056);      //   524,288
  float*    W1bT   = (float*)(ws + 9273344);      //   524,288
  _Float16* W2h    = (_Float16*)(ws + 9797632);   //   131,072
  _Float16* W3h    = (_Float16*)(ws + 9928704);   //    32,768
  float*    b3p    = (float*)(ws + 9961472);      //       256

  if (ws_size < 9963808) return;   // leaves d_out poisoned -> clean failure

  prep_kernel<<<3745, 256, 0, stream>>>(Wih_f, Wih_b, W1, W2, W3, b3,
                                        WihT, W1aT, W1bT, W2h, W3h, b3p);
  xb_kernel<<<256, 256, 0, stream>>>(x, WihT, bih_f, bhh_f, bih_b, bhh_b, xb);
  lstm_kernel<<<2, 1024, 0, stream>>>(Whh_f, Whh_b, xb, outcat);
  ab_kernel<<<512, 512, 0, stream>>>(outcat, W1aT, W1bT, b1, aP, bP);
  mlp_kernel<<<2048, 256, 0, stream>>>(aP, bP, W2h, W3h, b2, b3p, (float*)d_out);
}

// Round 5
// 1626.908 us; speedup vs baseline: 1.1567x; 1.1567x over previous
//
#include <hip/hip_runtime.h>
#include <hip/hip_bf16.h>
#include <hip/hip_fp16.h>

// ---------------------------------------------------------------------------
// BiLSTM (N=512, D_IN=300, H=256) + pairwise 3-layer MLP (4H->H->H->50)
// + log_softmax, on MI355X.
//
//   lstm (round-5 structure): one block/direction, 512 threads.
//   thread = (gate g, unit jj): rows g*256+jj, g*256+jj+128.
//   Weights k[0,192) in 192 f16x2 VGPRs; k[192,256) in LDS (128 KB swizzled).
//   h broadcast via GLOBAL f16 double buffer (L1-resident, uniform uint4
//   loads on the VMEM pipe -> DS pipe freed). Gate exchange via quad
//   __shfl_xor (DPP, VALU pipe). ONE barrier per step.
// ---------------------------------------------------------------------------

typedef _Float16 f16x2 __attribute__((ext_vector_type(2)));
typedef _Float16 f16x8 __attribute__((ext_vector_type(8)));
typedef float    f32x16 __attribute__((ext_vector_type(16)));

__device__ __forceinline__ float sigf(float x){ return 1.f/(1.f + __expf(-x)); }
__device__ __forceinline__ float dot2f(f16x2 a, f16x2 b, float c){
#if __has_builtin(__builtin_amdgcn_fdot2)
  return __builtin_amdgcn_fdot2(a, b, c, false);
#else
  return c + (float)a[0]*(float)b[0] + (float)a[1]*(float)b[1];
#endif
}
__device__ __forceinline__ f16x2 asf16x2(unsigned u){
  f16x2 r; __builtin_memcpy(&r, &u, 4); return r;
}
// arr[idx] for idx in 0..3 without memory (2 cndmasks)
__device__ __forceinline__ float sel4(float a0, float a1, float a2, float a3, int idx){
  float lo = (idx & 1) ? a1 : a0;
  float hi = (idx & 1) ? a3 : a2;
  return (idx & 2) ? hi : lo;
}

// ------------------------------ prep ---------------------------------------
__global__ __launch_bounds__(256) void prep_kernel(
    const float* __restrict__ Wih_f, const float* __restrict__ Wih_b,
    const float* __restrict__ W1,    const float* __restrict__ W2,
    const float* __restrict__ W3,    const float* __restrict__ b3,
    float* __restrict__ WihT, float* __restrict__ W1aT, float* __restrict__ W1bT,
    _Float16* __restrict__ W2h, _Float16* __restrict__ W3h,
    float* __restrict__ b3p)
{
  int idx = blockIdx.x * 256 + threadIdx.x;
  if (idx < 614400){                     // WihT[d][c][r] = Wih_d[r][c]
    int d = idx / 307200, r2 = idx % 307200;
    int cc = r2 / 1024, rr = r2 % 1024;
    const float* src = d ? Wih_b : Wih_f;
    WihT[idx] = src[rr*300 + cc];
    return;
  }
  idx -= 614400;
  if (idx < 262144){                     // W1aT[c][p]=W1[p][c]; W1bT[c][p]=W1[p][512+c]
    int sel = idx / 131072, r2 = idx % 131072;
    int cc = r2 / 256, pp = r2 % 256;
    float v = W1[pp*1024 + sel*512 + cc];
    (sel ? W1bT : W1aT)[r2] = v;
    return;
  }
  idx -= 262144;
  if (idx < 65536){ W2h[idx] = (_Float16)W2[idx]; return; }
  idx -= 65536;
  if (idx < 16384){                      // W3h padded to [64][256]
    int n = idx >> 8, k = idx & 255;
    W3h[idx] = (n < 50) ? (_Float16)W3[n*256 + k] : (_Float16)0.f;
    return;
  }
  idx -= 16384;
  if (idx < 64){ b3p[idx] = (idx < 50) ? b3[idx] : 0.f; return; }
}

// ------------------------------ xb ------------------------------------------
__global__ __launch_bounds__(256) void xb_kernel(
    const float* __restrict__ x, const float* __restrict__ WihT,
    const float* __restrict__ bih_f, const float* __restrict__ bhh_f,
    const float* __restrict__ bih_b, const float* __restrict__ bhh_b,
    float* __restrict__ xb)
{
  const int tid = threadIdx.x;
  const int dir = blockIdx.x >> 7;
  const int t0  = (blockIdx.x & 127) * 4;
  __shared__ float xs[4][304];
  #pragma unroll
  for (int tt = 0; tt < 4; ++tt)
    if (tid < 75) ((float4*)xs[tt])[tid] = ((const float4*)(x + (size_t)(t0+tt)*300))[tid];
  __syncthreads();
  const float* W = WihT + dir*307200;
  float acc[4][4];
  #pragma unroll
  for (int r = 0; r < 4; ++r){
    #pragma unroll
    for (int tt = 0; tt < 4; ++tt) acc[r][tt] = 0.f;
  }
  for (int c = 0; c < 300; ++c){
    float x0 = xs[0][c], x1 = xs[1][c], x2 = xs[2][c], x3 = xs[3][c];
    #pragma unroll
    for (int r = 0; r < 4; ++r){
      float wv = W[c*1024 + r*256 + tid];
      acc[r][0] += wv*x0; acc[r][1] += wv*x1; acc[r][2] += wv*x2; acc[r][3] += wv*x3;
    }
  }
  const float* bih = dir ? bih_b : bih_f;
  const float* bhh = dir ? bhh_b : bhh_f;
  float* xbd = xb + (size_t)dir*512*1024;
  #pragma unroll
  for (int r = 0; r < 4; ++r){
    int R = r*256 + tid;
    float bias = bih[R] + bhh[R];
    #pragma unroll
    for (int tt = 0; tt < 4; ++tt)
      xbd[(size_t)(t0+tt)*1024 + R] = acc[r][tt] + bias;
  }
}

// ------------------------------ lstm ----------------------------------------
__global__ __launch_bounds__(512, 2) void lstm_kernel(
    const float* __restrict__ Whh_f, const float* __restrict__ Whh_b,
    const float* __restrict__ xb, float* __restrict__ outcat,
    _Float16* __restrict__ hglob)       // [2 dir][2 buf][256] f16
{
  extern __shared__ char smem[];
  _Float16* wlds = (_Float16*)smem;     // [1024 rows][64 ks swizzled] = 128 KB

  const int tid = threadIdx.x;
  const int dir = blockIdx.x;
  const int g   = tid & 3;
  const int jj  = tid >> 2;             // [0,128)
  const int rA  = g*256 + jj;
  const int rB  = rA + 128;
  const float* Whh = dir ? Whh_b : Whh_f;

  // ---- register weights, k in [0,192): 96 f16x2 per row
  f16x2 wA[96], wB[96];
  {
    const float4* pa = (const float4*)(Whh + (size_t)rA*256);
    const float4* pb = (const float4*)(Whh + (size_t)rB*256);
    #pragma unroll
    for (int q = 0; q < 48; ++q){
      float4 va = pa[q];
      f16x2 t0, t1;
      t0[0]=(_Float16)va.x; t0[1]=(_Float16)va.y;
      t1[0]=(_Float16)va.z; t1[1]=(_Float16)va.w;
      wA[2*q] = t0; wA[2*q+1] = t1;
      float4 vb = pb[q];
      t0[0]=(_Float16)vb.x; t0[1]=(_Float16)vb.y;
      t1[0]=(_Float16)vb.z; t1[1]=(_Float16)vb.w;
      wB[2*q] = t0; wB[2*q+1] = t1;
    }
  }
  // ---- LDS weights, k in [192,256), XOR-swizzled rows (rA&7 == rB&7)
  const int sw = (rA & 7) << 4;
  {
    #pragma unroll
    for (int cc = 0; cc < 8; ++cc){
      float4 v0 = *(const float4*)(Whh + (size_t)rA*256 + 192 + cc*8);
      float4 v1 = *(const float4*)(Whh + (size_t)rA*256 + 192 + cc*8 + 4);
      f16x8 o;
      o[0]=(_Float16)v0.x; o[1]=(_Float16)v0.y; o[2]=(_Float16)v0.z; o[3]=(_Float16)v0.w;
      o[4]=(_Float16)v1.x; o[5]=(_Float16)v1.y; o[6]=(_Float16)v1.z; o[7]=(_Float16)v1.w;
      *(f16x8*)((char*)wlds + rA*128 + ((cc*16) ^ sw)) = o;
      v0 = *(const float4*)(Whh + (size_t)rB*256 + 192 + cc*8);
      v1 = *(const float4*)(Whh + (size_t)rB*256 + 192 + cc*8 + 4);
      o[0]=(_Float16)v0.x; o[1]=(_Float16)v0.y; o[2]=(_Float16)v0.z; o[3]=(_Float16)v0.w;
      o[4]=(_Float16)v1.x; o[5]=(_Float16)v1.y; o[6]=(_Float16)v1.z; o[7]=(_Float16)v1.w;
      *(f16x8*)((char*)wlds + rB*128 + ((cc*16) ^ sw)) = o;
    }
  }
  // ---- h_{-1} = 0 into global buf0 (L1-resident, 512 B)
  _Float16* hg = hglob + dir*512;       // [2 buf][256]
  if (tid < 32) ((float4*)hg)[tid] = make_float4(0.f,0.f,0.f,0.f);
  __syncthreads();

  // per-lane activation constants: gate 2 (cell) uses tanh = 2*sig(2x)-1
  const float sx = (g==2) ? 2.f : 1.f;
  const float m2 = (g==2) ? 2.f : 1.f;
  const float m3 = (g==2) ? -1.f : 0.f;

  const float* xbd = xb + (size_t)dir*512*1024;
  float c0 = 0.f, c1 = 0.f;

  for (int it = 0; it < 512; ++it){
    const int t = dir ? (511 - it) : it;
    const float xv0 = xbd[(size_t)t*1024 + rA];
    const float xv1 = xbd[(size_t)t*1024 + rB];
    const uint4* hbv = (const uint4*)(hg + (it & 1)*256);

    float a0=0.f, a1=0.f, a2=0.f, a3=0.f;
    float b0=0.f, b1=0.f, b2=0.f, b3=0.f;
    #pragma unroll
    for (int cc = 0; cc < 24; ++cc){            // k in [0,192): VMEM uniform
      uint4 hv = hbv[cc];
      f16x2 h0 = asf16x2(hv.x), h1 = asf16x2(hv.y);
      f16x2 h2 = asf16x2(hv.z), h3 = asf16x2(hv.w);
      a0 = dot2f(wA[4*cc+0], h0, a0); a1 = dot2f(wA[4*cc+1], h1, a1);
      a2 = dot2f(wA[4*cc+2], h2, a2); a3 = dot2f(wA[4*cc+3], h3, a3);
      b0 = dot2f(wB[4*cc+0], h0, b0); b1 = dot2f(wB[4*cc+1], h1, b1);
      b2 = dot2f(wB[4*cc+2], h2, b2); b3 = dot2f(wB[4*cc+3], h3, b3);
    }
    #pragma unroll
    for (int cc = 0; cc < 8; ++cc){             // k in [192,256): weights LDS
      uint4 hv = hbv[24+cc];
      f16x8 wa = *(const f16x8*)((char*)wlds + rA*128 + ((cc*16) ^ sw));
      f16x8 wb = *(const f16x8*)((char*)wlds + rB*128 + ((cc*16) ^ sw));
      a0 = dot2f(__builtin_shufflevector(wa,wa,0,1), asf16x2(hv.x), a0);
      a1 = dot2f(__builtin_shufflevector(wa,wa,2,3), asf16x2(hv.y), a1);
      a2 = dot2f(__builtin_shufflevector(wa,wa,4,5), asf16x2(hv.z), a2);
      a3 = dot2f(__builtin_shufflevector(wa,wa,6,7), asf16x2(hv.w), a3);
      b0 = dot2f(__builtin_shufflevector(wb,wb,0,1), asf16x2(hv.x), b0);
      b1 = dot2f(__builtin_shufflevector(wb,wb,2,3), asf16x2(hv.y), b1);
      b2 = dot2f(__builtin_shufflevector(wb,wb,4,5), asf16x2(hv.z), b2);
      b3 = dot2f(__builtin_shufflevector(wb,wb,6,7), asf16x2(hv.w), b3);
    }
    const float gA = (a0 + a1) + (a2 + a3) + xv0;   // gate g, unit jj
    const float gB = (b0 + b1) + (b2 + b3) + xv1;   // gate g, unit jj+128
    const float actA = fmaf(sigf(sx * gA), m2, m3);
    const float actB = fmaf(sigf(sx * gB), m2, m3);

    // quad all-gather (DPP): value from quad-lane with gate q = arr[g^q]
    const float A1 = __shfl_xor(actA, 1);
    const float A2 = __shfl_xor(actA, 2);
    const float A3 = __shfl_xor(A1, 2);
    const float B1 = __shfl_xor(actB, 1);
    const float B2 = __shfl_xor(actB, 2);
    const float B3 = __shfl_xor(B1, 2);
    const float viA = sel4(actA, A1, A2, A3, g);
    const float vfA = sel4(actA, A1, A2, A3, g ^ 1);
    const float vgA = sel4(actA, A1, A2, A3, g ^ 2);
    const float voA = sel4(actA, A1, A2, A3, g ^ 3);
    const float viB = sel4(actB, B1, B2, B3, g);
    const float vfB = sel4(actB, B1, B2, B3, g ^ 1);
    const float vgB = sel4(actB, B1, B2, B3, g ^ 2);
    const float voB = sel4(actB, B1, B2, B3, g ^ 3);

    c0 = fmaf(vfA, c0, viA * vgA);
    c1 = fmaf(vfB, c1, viB * vgB);
    const float h0 = voA * fmaf(sigf(2.f * c0), 2.f, -1.f);
    const float h1 = voB * fmaf(sigf(2.f * c1), 2.f, -1.f);

    if (g == 0){
      _Float16* hn = hg + ((it + 1) & 1)*256;
      hn[jj]       = (_Float16)h0;
      hn[jj + 128] = (_Float16)h1;
      outcat[(size_t)t*512 + dir*256 + jj]       = h0;
      outcat[(size_t)t*512 + dir*256 + jj + 128] = h1;
    }
    __syncthreads();    // vmcnt drained by barrier semantics -> h visible
  }
}

// ------------------------------ ab ------------------------------------------
__global__ __launch_bounds__(512) void ab_kernel(
    const float* __restrict__ outcat, const float* __restrict__ W1aT,
    const float* __restrict__ W1bT,  const float* __restrict__ b1,
    float* __restrict__ aP, float* __restrict__ bP)
{
  __shared__ float orow[512];
  const int tid = threadIdx.x;
  const int i = blockIdx.x;
  if (tid < 128) ((float4*)orow)[tid] = ((const float4*)(outcat + (size_t)i*512))[tid];
  __syncthreads();
  const int p = tid & 255, sel = tid >> 8;
  const float* W = sel ? W1bT : W1aT;
  float acc = sel ? 0.f : b1[p];
  #pragma unroll 8
  for (int cc = 0; cc < 512; ++cc) acc += orow[cc] * W[cc*256 + p];
  (sel ? bP : aP)[(size_t)i*256 + p] = acc;
}

// ------------------------------ fused MLP -----------------------------------
__global__ __launch_bounds__(256, 2) void mlp_kernel(
    const float* __restrict__ aP, const float* __restrict__ bP,
    const _Float16* __restrict__ W2h, const _Float16* __restrict__ W3h,
    const float* __restrict__ b2, const float* __restrict__ b3p,
    float* __restrict__ outp)
{
  __shared__ _Float16 lds[32768];   // 64KB union: W2 quarter (32KB) / h2 (64KB)
  const int tid = threadIdx.x;
  const int wv  = tid >> 6;
  const int ln  = tid & 31;
  const int hi  = (tid >> 5) & 1;
  const int i     = blockIdx.x >> 2;
  const int jbase = (blockIdx.x & 3) * 128;
  const int j     = jbase + wv*32 + ln;

  f32x16 acc[8];
  #pragma unroll
  for (int nt = 0; nt < 8; ++nt){
    #pragma unroll
    for (int e = 0; e < 16; ++e) acc[nt][e] = 0.f;
  }

  const float* arow = aP + (size_t)i*256;
  const float* brow = bP + (size_t)j*256;

  for (int p = 0; p < 4; ++p){
    if (p) __syncthreads();
    { // stage W2 quarter: rows n=tid, 64 k's, st_16x32 XOR swizzle
      const _Float16* src = W2h + tid*256 + p*64;
      char* dst = (char*)lds + tid*128;
      const int sw = (tid & 7) << 4;
      #pragma unroll
      for (int cc = 0; cc < 8; ++cc){
        f16x8 v = *(const f16x8*)(src + cc*8);
        *(f16x8*)(dst + ((cc*16) ^ sw)) = v;
      }
    }
    __syncthreads();
    #pragma unroll
    for (int ktl = 0; ktl < 4; ++ktl){
      const int kg = (p*4 + ktl)*16 + hi*8;
      float4 a0 = *(const float4*)(arow + kg);
      float4 a1 = *(const float4*)(arow + kg + 4);
      float4 b0 = *(const float4*)(brow + kg);
      float4 b1v = *(const float4*)(brow + kg + 4);
      f16x8 af;
      af[0] = (_Float16)fmaxf(a0.x + b0.x, 0.f);
      af[1] = (_Float16)fmaxf(a0.y + b0.y, 0.f);
      af[2] = (_Float16)fmaxf(a0.z + b0.z, 0.f);
      af[3] = (_Float16)fmaxf(a0.w + b0.w, 0.f);
      af[4] = (_Float16)fmaxf(a1.x + b1v.x, 0.f);
      af[5] = (_Float16)fmaxf(a1.y + b1v.y, 0.f);
      af[6] = (_Float16)fmaxf(a1.z + b1v.z, 0.f);
      af[7] = (_Float16)fmaxf(a1.w + b1v.w, 0.f);
      const int kl2 = (ktl*16 + hi*8) * 2;
      #pragma unroll
      for (int nt = 0; nt < 8; ++nt){
        const int n = nt*32 + ln;
        f16x8 bf = *(const f16x8*)((char*)lds + n*128 + (kl2 ^ ((n & 7) << 4)));
        acc[nt] = __builtin_amdgcn_mfma_f32_32x32x16_f16(af, bf, acc[nt], 0, 0, 0);
      }
    }
  }
  __syncthreads();
  // h2 -> LDS [128 pairs][256 ch] f16, XOR-swizzled per pair-row
  #pragma unroll
  for (int nt = 0; nt < 8; ++nt){
    const int ch = nt*32 + ln;
    const float bb = b2[ch];
    #pragma unroll
    for (int r = 0; r < 16; ++r){
      const int pr = wv*32 + (r & 3) + 8*(r >> 2) + 4*hi;
      const float v = fmaxf(acc[nt][r] + bb, 0.f);
      *(_Float16*)((char*)lds + pr*512 + ((ch*2) ^ ((pr & 7) << 4))) = (_Float16)v;
    }
  }
  __syncthreads();
  // logits
  f32x16 acc2[2];
  #pragma unroll
  for (int nt = 0; nt < 2; ++nt){
    #pragma unroll
    for (int e = 0; e < 16; ++e) acc2[nt][e] = 0.f;
  }
  const int pr = wv*32 + ln;
  const int sw2 = (pr & 7) << 4;
  #pragma unroll
  for (int kt = 0; kt < 16; ++kt){
    const int kb = kt*16 + hi*8;
    f16x8 a2 = *(const f16x8*)((char*)lds + pr*512 + ((kb*2) ^ sw2));
    #pragma unroll
    for (int nt = 0; nt < 2; ++nt){
      const int n = nt*32 + ln;
      f16x8 bf = *(const f16x8*)(W3h + n*256 + kb);
      acc2[nt] = __builtin_amdgcn_mfma_f32_32x32x16_f16(a2, bf, acc2[nt], 0, 0, 0);
    }
  }
  // log_softmax over 50 classes
  const float b30 = b3p[ln], b31 = b3p[32 + ln];
  const bool ok2 = (ln < 18);
  #pragma unroll
  for (int qr = 0; qr < 16; ++qr){
    const int r = (qr & 3) + 8*(qr >> 2) + 4*hi;
    float v0 = acc2[0][qr] + b30;
    float v1 = acc2[1][qr] + b31;
    float m = ok2 ? fmaxf(v0, v1) : v0;
    #pragma unroll
    for (int d = 1; d < 32; d <<= 1) m = fmaxf(m, __shfl_xor(m, d));
    float s = __expf(v0 - m) + (ok2 ? __expf(v1 - m) : 0.f);
    #pragma unroll
    for (int d = 1; d < 32; d <<= 1) s += __shfl_xor(s, d);
    const float lse = m + __logf(s);
    const size_t base = ((size_t)(i*512 + jbase + wv*32 + r)) * 50;
    outp[base + ln] = v0 - lse;
    if (ok2) outp[base + 32 + ln] = v1 - lse;
  }
}

// ------------------------------ launch --------------------------------------
extern "C" void kernel_launch(void* const* d_in, const int* in_sizes, int n_in,
                              void* d_out, int out_size, void* d_ws, size_t ws_size,
                              hipStream_t stream)
{
  const float* x     = (const float*)d_in[0];
  const float* Wih_f = (const float*)d_in[1];
  const float* Whh_f = (const float*)d_in[2];
  const float* bih_f = (const float*)d_in[3];
  const float* bhh_f = (const float*)d_in[4];
  const float* Wih_b = (const float*)d_in[5];
  const float* Whh_b = (const float*)d_in[6];
  const float* bih_b = (const float*)d_in[7];
  const float* bhh_b = (const float*)d_in[8];
  const float* W1    = (const float*)d_in[9];
  const float* b1    = (const float*)d_in[10];
  const float* W2    = (const float*)d_in[11];
  const float* b2    = (const float*)d_in[12];
  const float* W3    = (const float*)d_in[13];
  const float* b3    = (const float*)d_in[14];

  char* ws = (char*)d_ws;
  float*    xb     = (float*)(ws + 0);            // 4,194,304
  float*    outcat = (float*)(ws + 4194304);      // 1,048,576
  float*    aP     = (float*)(ws + 5242880);      //   524,288
  float*    bP     = (float*)(ws + 5767168);      //   524,288
  float*    WihT   = (float*)(ws + 6291456);      // 2,457,600
  float*    W1aT   = (float*)(ws + 8749056);      //   524,288
  float*    W1bT   = (float*)(ws + 9273344);      //   524,288
  _Float16* W2h    = (_Float16*)(ws + 9797632);   //   131,072
  _Float16* W3h    = (_Float16*)(ws + 9928704);   //    32,768
  float*    b3p    = (float*)(ws + 9961472);      //       256
  _Float16* hglob  = (_Float16*)(ws + 9961728);   //     2,048

  if (ws_size < 9963808) return;   // leaves d_out poisoned -> clean failure

  // lstm needs 131,072 B of dynamic LDS (>64 KB static limit)
  (void)hipFuncSetAttribute((const void*)lstm_kernel,
                            hipFuncAttributeMaxDynamicSharedMemorySize, 131072);

  prep_kernel<<<3745, 256, 0, stream>>>(Wih_f, Wih_b, W1, W2, W3, b3,
                                        WihT, W1aT, W1bT, W2h, W3h, b3p);
  xb_kernel<<<256, 256, 0, stream>>>(x, WihT, bih_f, bhh_f, bih_b, bhh_b, xb);
  lstm_kernel<<<2, 512, 131072, stream>>>(Whh_f, Whh_b, xb, outcat, hglob);
  ab_kernel<<<512, 512, 0, stream>>>(outcat, W1aT, W1bT, b1, aP, bP);
  mlp_kernel<<<2048, 256, 0, stream>>>(aP, bP, W2h, W3h, b2, b3p, (float*)d_out);
}

// Round 6
// 1593.805 us; speedup vs baseline: 1.1808x; 1.0208x over previous
//
#include <hip/hip_runtime.h>
#include <hip/hip_bf16.h>
#include <hip/hip_fp16.h>

// ---------------------------------------------------------------------------
// BiLSTM (N=512, D_IN=300, H=256) + pairwise 3-layer MLP (4H->H->H->50)
// + log_softmax, on MI355X.
//
//   lstm (round-6): one block/direction, 1024 threads, thread = (gate g,
//   unit j) owns ONE Whh row. 96 f16x2 weights in ARCH VGPRs (fits the
//   128-reg cap at 4 waves/SIMD -> real v_dot2_f32_f16, no AGPR moves),
//   k[192,256) in LDS (128 KB XOR-swizzled). h broadcast via LDS uniform
//   b128 reads; gates exchanged with quad __shfl_xor; ONE barrier/step.
// ---------------------------------------------------------------------------

typedef _Float16 f16x2 __attribute__((ext_vector_type(2)));
typedef _Float16 f16x8 __attribute__((ext_vector_type(8)));
typedef float    f32x16 __attribute__((ext_vector_type(16)));

__device__ __forceinline__ float sigf(float x){ return 1.f/(1.f + __expf(-x)); }
// Packed dot on VGPR operands (weights are arch-VGPR resident by design).
__device__ __forceinline__ float dot2f(f16x2 a, f16x2 b, float c){
  float d;
  asm("v_dot2_f32_f16 %0, %1, %2, %3" : "=v"(d) : "v"(a), "v"(b), "v"(c));
  return d;
}
__device__ __forceinline__ float sel4(float a0, float a1, float a2, float a3, int idx){
  float lo = (idx & 1) ? a1 : a0;
  float hi = (idx & 1) ? a3 : a2;
  return (idx & 2) ? hi : lo;
}

// ------------------------------ prep ---------------------------------------
__global__ __launch_bounds__(256) void prep_kernel(
    const float* __restrict__ Wih_f, const float* __restrict__ Wih_b,
    const float* __restrict__ W1,    const float* __restrict__ W2,
    const float* __restrict__ W3,    const float* __restrict__ b3,
    float* __restrict__ WihT, float* __restrict__ W1aT, float* __restrict__ W1bT,
    _Float16* __restrict__ W2h, _Float16* __restrict__ W3h,
    float* __restrict__ b3p)
{
  int idx = blockIdx.x * 256 + threadIdx.x;
  if (idx < 614400){                     // WihT[d][c][r] = Wih_d[r][c]
    int d = idx / 307200, r2 = idx % 307200;
    int cc = r2 / 1024, rr = r2 % 1024;
    const float* src = d ? Wih_b : Wih_f;
    WihT[idx] = src[rr*300 + cc];
    return;
  }
  idx -= 614400;
  if (idx < 262144){                     // W1aT[c][p]=W1[p][c]; W1bT[c][p]=W1[p][512+c]
    int sel = idx / 131072, r2 = idx % 131072;
    int cc = r2 / 256, pp = r2 % 256;
    float v = W1[pp*1024 + sel*512 + cc];
    (sel ? W1bT : W1aT)[r2] = v;
    return;
  }
  idx -= 262144;
  if (idx < 65536){ W2h[idx] = (_Float16)W2[idx]; return; }
  idx -= 65536;
  if (idx < 16384){                      // W3h padded to [64][256]
    int n = idx >> 8, k = idx & 255;
    W3h[idx] = (n < 50) ? (_Float16)W3[n*256 + k] : (_Float16)0.f;
    return;
  }
  idx -= 16384;
  if (idx < 64){ b3p[idx] = (idx < 50) ? b3[idx] : 0.f; return; }
}

// ------------------------------ xb ------------------------------------------
__global__ __launch_bounds__(256) void xb_kernel(
    const float* __restrict__ x, const float* __restrict__ WihT,
    const float* __restrict__ bih_f, const float* __restrict__ bhh_f,
    const float* __restrict__ bih_b, const float* __restrict__ bhh_b,
    float* __restrict__ xb)
{
  const int tid = threadIdx.x;
  const int dir = blockIdx.x >> 7;
  const int t0  = (blockIdx.x & 127) * 4;
  __shared__ float xs[4][304];
  #pragma unroll
  for (int tt = 0; tt < 4; ++tt)
    if (tid < 75) ((float4*)xs[tt])[tid] = ((const float4*)(x + (size_t)(t0+tt)*300))[tid];
  __syncthreads();
  const float* W = WihT + dir*307200;
  float acc[4][4];
  #pragma unroll
  for (int r = 0; r < 4; ++r){
    #pragma unroll
    for (int tt = 0; tt < 4; ++tt) acc[r][tt] = 0.f;
  }
  for (int c = 0; c < 300; ++c){
    float x0 = xs[0][c], x1 = xs[1][c], x2 = xs[2][c], x3 = xs[3][c];
    #pragma unroll
    for (int r = 0; r < 4; ++r){
      float wv = W[c*1024 + r*256 + tid];
      acc[r][0] += wv*x0; acc[r][1] += wv*x1; acc[r][2] += wv*x2; acc[r][3] += wv*x3;
    }
  }
  const float* bih = dir ? bih_b : bih_f;
  const float* bhh = dir ? bhh_b : bhh_f;
  float* xbd = xb + (size_t)dir*512*1024;
  #pragma unroll
  for (int r = 0; r < 4; ++r){
    int R = r*256 + tid;
    float bias = bih[R] + bhh[R];
    #pragma unroll
    for (int tt = 0; tt < 4; ++tt)
      xbd[(size_t)(t0+tt)*1024 + R] = acc[r][tt] + bias;
  }
}

// ------------------------------ lstm ----------------------------------------
__global__ __launch_bounds__(1024, 4) void lstm_kernel(
    const float* __restrict__ Whh_f, const float* __restrict__ Whh_b,
    const float* __restrict__ xb, float* __restrict__ outcat)
{
  extern __shared__ char smem[];
  _Float16* wlds = (_Float16*)smem;              // [1024 rows][64 k] swz = 128 KB
  _Float16* hbuf = (_Float16*)(smem + 131072);   // [2][256] = 1 KB

  const int tid = threadIdx.x;
  const int dir = blockIdx.x;
  const int g   = tid & 3;
  const int j   = tid >> 2;
  const int row = g*256 + j;
  const float* Whh = dir ? Whh_b : Whh_f;
  const float4* wp = (const float4*)(Whh + (size_t)row*256);

  // ---- k[0,192): 96 f16x2 in arch VGPRs
  f16x2 w[96];
  #pragma unroll
  for (int q = 0; q < 48; ++q){
    float4 v = wp[q];
    f16x2 t0, t1;
    t0[0]=(_Float16)v.x; t0[1]=(_Float16)v.y;
    t1[0]=(_Float16)v.z; t1[1]=(_Float16)v.w;
    w[2*q] = t0; w[2*q+1] = t1;
  }
  // ---- k[192,256): LDS, XOR-swizzled (row stride 128 B)
  const int sw = (row & 7) << 4;
  #pragma unroll
  for (int cc = 0; cc < 8; ++cc){
    float4 v0 = wp[48 + cc*2];
    float4 v1 = wp[48 + cc*2 + 1];
    f16x8 o;
    o[0]=(_Float16)v0.x; o[1]=(_Float16)v0.y; o[2]=(_Float16)v0.z; o[3]=(_Float16)v0.w;
    o[4]=(_Float16)v1.x; o[5]=(_Float16)v1.y; o[6]=(_Float16)v1.z; o[7]=(_Float16)v1.w;
    *(f16x8*)((char*)wlds + row*128 + ((cc*16) ^ sw)) = o;
  }
  if (tid < 32) ((f16x8*)hbuf)[tid] = (f16x8)(_Float16)0.f;   // h_{-1} = 0
  __syncthreads();

  // gate 2 (cell) uses tanh = 2*sig(2x)-1; others sigmoid
  const float sx = (g==2) ? 2.f : 1.f;
  const float m2 = (g==2) ? 2.f : 1.f;
  const float m3 = (g==2) ? -1.f : 0.f;

  const float* xbd = xb + (size_t)dir*512*1024;
  float cst = 0.f;

  for (int it = 0; it < 512; ++it){
    const int t = dir ? (511 - it) : it;
    const float xv = xbd[(size_t)t*1024 + row];   // issued early, used late
    const f16x8* hb = (const f16x8*)(hbuf + (it & 1)*256);

    float a0=0.f, a1=0.f, a2=0.f, a3=0.f;
    #pragma unroll
    for (int cc = 0; cc < 24; ++cc){              // k[0,192): VGPR weights
      f16x8 hv = hb[cc];                          // uniform -> LDS broadcast
      a0 = dot2f(w[4*cc+0], __builtin_shufflevector(hv, hv, 0, 1), a0);
      a1 = dot2f(w[4*cc+1], __builtin_shufflevector(hv, hv, 2, 3), a1);
      a2 = dot2f(w[4*cc+2], __builtin_shufflevector(hv, hv, 4, 5), a2);
      a3 = dot2f(w[4*cc+3], __builtin_shufflevector(hv, hv, 6, 7), a3);
    }
    #pragma unroll
    for (int cc = 0; cc < 8; ++cc){               // k[192,256): LDS weights
      f16x8 hv = hb[24+cc];
      f16x8 wa = *(const f16x8*)((char*)wlds + row*128 + ((cc*16) ^ sw));
      a0 = dot2f(__builtin_shufflevector(wa,wa,0,1), __builtin_shufflevector(hv,hv,0,1), a0);
      a1 = dot2f(__builtin_shufflevector(wa,wa,2,3), __builtin_shufflevector(hv,hv,2,3), a1);
      a2 = dot2f(__builtin_shufflevector(wa,wa,4,5), __builtin_shufflevector(hv,hv,4,5), a2);
      a3 = dot2f(__builtin_shufflevector(wa,wa,6,7), __builtin_shufflevector(hv,hv,6,7), a3);
    }
    const float gv = (a0 + a1) + (a2 + a3) + xv;
    const float act = fmaf(sigf(sx * gv), m2, m3);

    // quad all-gather: value from quad-lane with gate q is arr[g^q]
    const float A1 = __shfl_xor(act, 1);
    const float A2 = __shfl_xor(act, 2);
    const float A3 = __shfl_xor(A1, 2);
    const float vi = sel4(act, A1, A2, A3, g);
    const float vf = sel4(act, A1, A2, A3, g ^ 1);
    const float vg = sel4(act, A1, A2, A3, g ^ 2);
    const float vo = sel4(act, A1, A2, A3, g ^ 3);

    cst = fmaf(vf, cst, vi * vg);                 // redundant per quad
    const float h = vo * fmaf(sigf(2.f * cst), 2.f, -1.f);
    if (g == 0){
      hbuf[((it + 1) & 1)*256 + j] = (_Float16)h;
      outcat[(size_t)t*512 + dir*256 + j] = h;
    }
    __syncthreads();
  }
}

// ------------------------------ ab ------------------------------------------
__global__ __launch_bounds__(512) void ab_kernel(
    const float* __restrict__ outcat, const float* __restrict__ W1aT,
    const float* __restrict__ W1bT,  const float* __restrict__ b1,
    float* __restrict__ aP, float* __restrict__ bP)
{
  __shared__ float orow[512];
  const int tid = threadIdx.x;
  const int i = blockIdx.x;
  if (tid < 128) ((float4*)orow)[tid] = ((const float4*)(outcat + (size_t)i*512))[tid];
  __syncthreads();
  const int p = tid & 255, sel = tid >> 8;
  const float* W = sel ? W1bT : W1aT;
  float acc = sel ? 0.f : b1[p];
  #pragma unroll 8
  for (int cc = 0; cc < 512; ++cc) acc += orow[cc] * W[cc*256 + p];
  (sel ? bP : aP)[(size_t)i*256 + p] = acc;
}

// ------------------------------ fused MLP -----------------------------------
__global__ __launch_bounds__(256, 2) void mlp_kernel(
    const float* __restrict__ aP, const float* __restrict__ bP,
    const _Float16* __restrict__ W2h, const _Float16* __restrict__ W3h,
    const float* __restrict__ b2, const float* __restrict__ b3p,
    float* __restrict__ outp)
{
  __shared__ _Float16 lds[32768];   // 64KB union: W2 quarter (32KB) / h2 (64KB)
  const int tid = threadIdx.x;
  const int wv  = tid >> 6;
  const int ln  = tid & 31;
  const int hi  = (tid >> 5) & 1;
  const int i     = blockIdx.x >> 2;
  const int jbase = (blockIdx.x & 3) * 128;
  const int j     = jbase + wv*32 + ln;

  f32x16 acc[8];
  #pragma unroll
  for (int nt = 0; nt < 8; ++nt){
    #pragma unroll
    for (int e = 0; e < 16; ++e) acc[nt][e] = 0.f;
  }

  const float* arow = aP + (size_t)i*256;
  const float* brow = bP + (size_t)j*256;

  for (int p = 0; p < 4; ++p){
    if (p) __syncthreads();
    { // stage W2 quarter: rows n=tid, 64 k's, st_16x32 XOR swizzle
      const _Float16* src = W2h + tid*256 + p*64;
      char* dst = (char*)lds + tid*128;
      const int sw = (tid & 7) << 4;
      #pragma unroll
      for (int cc = 0; cc < 8; ++cc){
        f16x8 v = *(const f16x8*)(src + cc*8);
        *(f16x8*)(dst + ((cc*16) ^ sw)) = v;
      }
    }
    __syncthreads();
    #pragma unroll
    for (int ktl = 0; ktl < 4; ++ktl){
      const int kg = (p*4 + ktl)*16 + hi*8;
      float4 a0 = *(const float4*)(arow + kg);
      float4 a1 = *(const float4*)(arow + kg + 4);
      float4 b0 = *(const float4*)(brow + kg);
      float4 b1v = *(const float4*)(brow + kg + 4);
      f16x8 af;
      af[0] = (_Float16)fmaxf(a0.x + b0.x, 0.f);
      af[1] = (_Float16)fmaxf(a0.y + b0.y, 0.f);
      af[2] = (_Float16)fmaxf(a0.z + b0.z, 0.f);
      af[3] = (_Float16)fmaxf(a0.w + b0.w, 0.f);
      af[4] = (_Float16)fmaxf(a1.x + b1v.x, 0.f);
      af[5] = (_Float16)fmaxf(a1.y + b1v.y, 0.f);
      af[6] = (_Float16)fmaxf(a1.z + b1v.z, 0.f);
      af[7] = (_Float16)fmaxf(a1.w + b1v.w, 0.f);
      const int kl2 = (ktl*16 + hi*8) * 2;
      #pragma unroll
      for (int nt = 0; nt < 8; ++nt){
        const int n = nt*32 + ln;
        f16x8 bf = *(const f16x8*)((char*)lds + n*128 + (kl2 ^ ((n & 7) << 4)));
        acc[nt] = __builtin_amdgcn_mfma_f32_32x32x16_f16(af, bf, acc[nt], 0, 0, 0);
      }
    }
  }
  __syncthreads();
  // h2 -> LDS [128 pairs][256 ch] f16, XOR-swizzled per pair-row
  #pragma unroll
  for (int nt = 0; nt < 8; ++nt){
    const int ch = nt*32 + ln;
    const float bb = b2[ch];
    #pragma unroll
    for (int r = 0; r < 16; ++r){
      const int pr = wv*32 + (r & 3) + 8*(r >> 2) + 4*hi;
      const float v = fmaxf(acc[nt][r] + bb, 0.f);
      *(_Float16*)((char*)lds + pr*512 + ((ch*2) ^ ((pr & 7) << 4))) = (_Float16)v;
    }
  }
  __syncthreads();
  // logits
  f32x16 acc2[2];
  #pragma unroll
  for (int nt = 0; nt < 2; ++nt){
    #pragma unroll
    for (int e = 0; e < 16; ++e) acc2[nt][e] = 0.f;
  }
  const int pr = wv*32 + ln;
  const int sw2 = (pr & 7) << 4;
  #pragma unroll
  for (int kt = 0; kt < 16; ++kt){
    const int kb = kt*16 + hi*8;
    f16x8 a2 = *(const f16x8*)((char*)lds + pr*512 + ((kb*2) ^ sw2));
    #pragma unroll
    for (int nt = 0; nt < 2; ++nt){
      const int n = nt*32 + ln;
      f16x8 bf = *(const f16x8*)(W3h + n*256 + kb);
      acc2[nt] = __builtin_amdgcn_mfma_f32_32x32x16_f16(a2, bf, acc2[nt], 0, 0, 0);
    }
  }
  // log_softmax over 50 classes
  const float b30 = b3p[ln], b31 = b3p[32 + ln];
  const bool ok2 = (ln < 18);
  #pragma unroll
  for (int qr = 0; qr < 16; ++qr){
    const int r = (qr & 3) + 8*(qr >> 2) + 4*hi;
    float v0 = acc2[0][qr] + b30;
    float v1 = acc2[1][qr] + b31;
    float m = ok2 ? fmaxf(v0, v1) : v0;
    #pragma unroll
    for (int d = 1; d < 32; d <<= 1) m = fmaxf(m, __shfl_xor(m, d));
    float s = __expf(v0 - m) + (ok2 ? __expf(v1 - m) : 0.f);
    #pragma unroll
    for (int d = 1; d < 32; d <<= 1) s += __shfl_xor(s, d);
    const float lse = m + __logf(s);
    const size_t base = ((size_t)(i*512 + jbase + wv*32 + r)) * 50;
    outp[base + ln] = v0 - lse;
    if (ok2) outp[base + 32 + ln] = v1 - lse;
  }
}

// ------------------------------ launch --------------------------------------
extern "C" void kernel_launch(void* const* d_in, const int* in_sizes, int n_in,
                              void* d_out, int out_size, void* d_ws, size_t ws_size,
                              hipStream_t stream)
{
  const float* x     = (const float*)d_in[0];
  const float* Wih_f = (const float*)d_in[1];
  const float* Whh_f = (const float*)d_in[2];
  const float* bih_f = (const float*)d_in[3];
  const float* bhh_f = (const float*)d_in[4];
  const float* Wih_b = (const float*)d_in[5];
  const float* Whh_b = (const float*)d_in[6];
  const float* bih_b = (const float*)d_in[7];
  const float* bhh_b = (const float*)d_in[8];
  const float* W1    = (const float*)d_in[9];
  const float* b1    = (const float*)d_in[10];
  const float* W2    = (const float*)d_in[11];
  const float* b2    = (const float*)d_in[12];
  const float* W3    = (const float*)d_in[13];
  const float* b3    = (const float*)d_in[14];

  char* ws = (char*)d_ws;
  float*    xb     = (float*)(ws + 0);            // 4,194,304
  float*    outcat = (float*)(ws + 4194304);      // 1,048,576
  float*    aP     = (float*)(ws + 5242880);      //   524,288
  float*    bP     = (float*)(ws + 5767168);      //   524,288
  float*    WihT   = (float*)(ws + 6291456);      // 2,457,600
  float*    W1aT   = (float*)(ws + 8749056);      //   524,288
  float*    W1bT   = (float*)(ws + 9273344);      //   524,288
  _Float16* W2h    = (_Float16*)(ws + 9797632);   //   131,072
  _Float16* W3h    = (_Float16*)(ws + 9928704);   //    32,768
  float*    b3p    = (float*)(ws + 9961472);      //       256

  if (ws_size < 9963808) return;   // leaves d_out poisoned -> clean failure

  // lstm needs 132,096 B of dynamic LDS (>64 KB static limit)
  (void)hipFuncSetAttribute((const void*)lstm_kernel,
                            hipFuncAttributeMaxDynamicSharedMemorySize, 132096);

  prep_kernel<<<3745, 256, 0, stream>>>(Wih_f, Wih_b, W1, W2, W3, b3,
                                        WihT, W1aT, W1bT, W2h, W3h, b3p);
  xb_kernel<<<256, 256, 0, stream>>>(x, WihT, bih_f, bhh_f, bih_b, bhh_b, xb);
  lstm_kernel<<<2, 1024, 132096, stream>>>(Whh_f, Whh_b, xb, outcat);
  ab_kernel<<<512, 512, 0, stream>>>(outcat, W1aT, W1bT, b1, aP, bP);
  mlp_kernel<<<2048, 256, 0, stream>>>(aP, bP, W2h, W3h, b2, b3p, (float*)d_out);
}

// Round 7
// 1579.431 us; speedup vs baseline: 1.1915x; 1.0091x over previous
//
#include <hip/hip_runtime.h>
#include <hip/hip_bf16.h>
#include <hip/hip_fp16.h>

// ---------------------------------------------------------------------------
// BiLSTM (N=512, D_IN=300, H=256) + pairwise 3-layer MLP (4H->H->H->50)
// + log_softmax, on MI355X.
//
//   lstm (round-7): identical structure to round-6 (one block/direction,
//   1024 threads, thread=(gate,unit) owns one Whh row; 96 f16x2 weights in
//   arch VGPRs, k[192,256) in 128 KB XOR-swizzled LDS; h via LDS uniform
//   b128; quad __shfl_xor gate exchange; 1 barrier/step) with ONE change:
//   amdgpu_waves_per_eu(4,4) pins the occupancy target so the compiler
//   allocates 128 arch VGPRs (r4/r6 allocated only 64 because the dynamic
//   LDS size was invisible and it optimized for 8 waves/EU, pushing the
//   weight array into AGPRs and paying v_accvgpr_read on every dot).
// ---------------------------------------------------------------------------

typedef _Float16 f16x2 __attribute__((ext_vector_type(2)));
typedef _Float16 f16x8 __attribute__((ext_vector_type(8)));
typedef float    f32x16 __attribute__((ext_vector_type(16)));

__device__ __forceinline__ float sigf(float x){ return 1.f/(1.f + __expf(-x)); }
// Packed dot on VGPR operands (weights are arch-VGPR resident by design).
__device__ __forceinline__ float dot2f(f16x2 a, f16x2 b, float c){
  float d;
  asm("v_dot2_f32_f16 %0, %1, %2, %3" : "=v"(d) : "v"(a), "v"(b), "v"(c));
  return d;
}
__device__ __forceinline__ float sel4(float a0, float a1, float a2, float a3, int idx){
  float lo = (idx & 1) ? a1 : a0;
  float hi = (idx & 1) ? a3 : a2;
  return (idx & 2) ? hi : lo;
}

// ------------------------------ prep ---------------------------------------
__global__ __launch_bounds__(256) void prep_kernel(
    const float* __restrict__ Wih_f, const float* __restrict__ Wih_b,
    const float* __restrict__ W1,    const float* __restrict__ W2,
    const float* __restrict__ W3,    const float* __restrict__ b3,
    float* __restrict__ WihT, float* __restrict__ W1aT, float* __restrict__ W1bT,
    _Float16* __restrict__ W2h, _Float16* __restrict__ W3h,
    float* __restrict__ b3p)
{
  int idx = blockIdx.x * 256 + threadIdx.x;
  if (idx < 614400){                     // WihT[d][c][r] = Wih_d[r][c]
    int d = idx / 307200, r2 = idx % 307200;
    int cc = r2 / 1024, rr = r2 % 1024;
    const float* src = d ? Wih_b : Wih_f;
    WihT[idx] = src[rr*300 + cc];
    return;
  }
  idx -= 614400;
  if (idx < 262144){                     // W1aT[c][p]=W1[p][c]; W1bT[c][p]=W1[p][512+c]
    int sel = idx / 131072, r2 = idx % 131072;
    int cc = r2 / 256, pp = r2 % 256;
    float v = W1[pp*1024 + sel*512 + cc];
    (sel ? W1bT : W1aT)[r2] = v;
    return;
  }
  idx -= 262144;
  if (idx < 65536){ W2h[idx] = (_Float16)W2[idx]; return; }
  idx -= 65536;
  if (idx < 16384){                      // W3h padded to [64][256]
    int n = idx >> 8, k = idx & 255;
    W3h[idx] = (n < 50) ? (_Float16)W3[n*256 + k] : (_Float16)0.f;
    return;
  }
  idx -= 16384;
  if (idx < 64){ b3p[idx] = (idx < 50) ? b3[idx] : 0.f; return; }
}

// ------------------------------ xb ------------------------------------------
__global__ __launch_bounds__(256) void xb_kernel(
    const float* __restrict__ x, const float* __restrict__ WihT,
    const float* __restrict__ bih_f, const float* __restrict__ bhh_f,
    const float* __restrict__ bih_b, const float* __restrict__ bhh_b,
    float* __restrict__ xb)
{
  const int tid = threadIdx.x;
  const int dir = blockIdx.x >> 7;
  const int t0  = (blockIdx.x & 127) * 4;
  __shared__ float xs[4][304];
  #pragma unroll
  for (int tt = 0; tt < 4; ++tt)
    if (tid < 75) ((float4*)xs[tt])[tid] = ((const float4*)(x + (size_t)(t0+tt)*300))[tid];
  __syncthreads();
  const float* W = WihT + dir*307200;
  float acc[4][4];
  #pragma unroll
  for (int r = 0; r < 4; ++r){
    #pragma unroll
    for (int tt = 0; tt < 4; ++tt) acc[r][tt] = 0.f;
  }
  for (int c = 0; c < 300; ++c){
    float x0 = xs[0][c], x1 = xs[1][c], x2 = xs[2][c], x3 = xs[3][c];
    #pragma unroll
    for (int r = 0; r < 4; ++r){
      float wv = W[c*1024 + r*256 + tid];
      acc[r][0] += wv*x0; acc[r][1] += wv*x1; acc[r][2] += wv*x2; acc[r][3] += wv*x3;
    }
  }
  const float* bih = dir ? bih_b : bih_f;
  const float* bhh = dir ? bhh_b : bhh_f;
  float* xbd = xb + (size_t)dir*512*1024;
  #pragma unroll
  for (int r = 0; r < 4; ++r){
    int R = r*256 + tid;
    float bias = bih[R] + bhh[R];
    #pragma unroll
    for (int tt = 0; tt < 4; ++tt)
      xbd[(size_t)(t0+tt)*1024 + R] = acc[r][tt] + bias;
  }
}

// ------------------------------ lstm ----------------------------------------
__global__ __launch_bounds__(1024)
__attribute__((amdgpu_waves_per_eu(4, 4)))
void lstm_kernel(
    const float* __restrict__ Whh_f, const float* __restrict__ Whh_b,
    const float* __restrict__ xb, float* __restrict__ outcat)
{
  extern __shared__ char smem[];
  _Float16* wlds = (_Float16*)smem;              // [1024 rows][64 k] swz = 128 KB
  _Float16* hbuf = (_Float16*)(smem + 131072);   // [2][256] = 1 KB

  const int tid = threadIdx.x;
  const int dir = blockIdx.x;
  const int g   = tid & 3;
  const int j   = tid >> 2;
  const int row = g*256 + j;
  const float* Whh = dir ? Whh_b : Whh_f;
  const float4* wp = (const float4*)(Whh + (size_t)row*256);

  // ---- k[0,192): 96 f16x2 in arch VGPRs
  f16x2 w[96];
  #pragma unroll
  for (int q = 0; q < 48; ++q){
    float4 v = wp[q];
    f16x2 t0, t1;
    t0[0]=(_Float16)v.x; t0[1]=(_Float16)v.y;
    t1[0]=(_Float16)v.z; t1[1]=(_Float16)v.w;
    w[2*q] = t0; w[2*q+1] = t1;
  }
  // ---- k[192,256): LDS, XOR-swizzled (row stride 128 B)
  const int sw = (row & 7) << 4;
  #pragma unroll
  for (int cc = 0; cc < 8; ++cc){
    float4 v0 = wp[48 + cc*2];
    float4 v1 = wp[48 + cc*2 + 1];
    f16x8 o;
    o[0]=(_Float16)v0.x; o[1]=(_Float16)v0.y; o[2]=(_Float16)v0.z; o[3]=(_Float16)v0.w;
    o[4]=(_Float16)v1.x; o[5]=(_Float16)v1.y; o[6]=(_Float16)v1.z; o[7]=(_Float16)v1.w;
    *(f16x8*)((char*)wlds + row*128 + ((cc*16) ^ sw)) = o;
  }
  if (tid < 32) ((f16x8*)hbuf)[tid] = (f16x8)(_Float16)0.f;   // h_{-1} = 0
  __syncthreads();

  // gate 2 (cell) uses tanh = 2*sig(2x)-1; others sigmoid
  const float sx = (g==2) ? 2.f : 1.f;
  const float m2 = (g==2) ? 2.f : 1.f;
  const float m3 = (g==2) ? -1.f : 0.f;

  const float* xbd = xb + (size_t)dir*512*1024;
  float cst = 0.f;

  for (int it = 0; it < 512; ++it){
    const int t = dir ? (511 - it) : it;
    const float xv = xbd[(size_t)t*1024 + row];   // issued early, used late
    const f16x8* hb = (const f16x8*)(hbuf + (it & 1)*256);

    float a0=0.f, a1=0.f, a2=0.f, a3=0.f;
    #pragma unroll
    for (int cc = 0; cc < 24; ++cc){              // k[0,192): VGPR weights
      f16x8 hv = hb[cc];                          // uniform -> LDS broadcast
      a0 = dot2f(w[4*cc+0], __builtin_shufflevector(hv, hv, 0, 1), a0);
      a1 = dot2f(w[4*cc+1], __builtin_shufflevector(hv, hv, 2, 3), a1);
      a2 = dot2f(w[4*cc+2], __builtin_shufflevector(hv, hv, 4, 5), a2);
      a3 = dot2f(w[4*cc+3], __builtin_shufflevector(hv, hv, 6, 7), a3);
    }
    #pragma unroll
    for (int cc = 0; cc < 8; ++cc){               // k[192,256): LDS weights
      f16x8 hv = hb[24+cc];
      f16x8 wa = *(const f16x8*)((char*)wlds + row*128 + ((cc*16) ^ sw));
      a0 = dot2f(__builtin_shufflevector(wa,wa,0,1), __builtin_shufflevector(hv,hv,0,1), a0);
      a1 = dot2f(__builtin_shufflevector(wa,wa,2,3), __builtin_shufflevector(hv,hv,2,3), a1);
      a2 = dot2f(__builtin_shufflevector(wa,wa,4,5), __builtin_shufflevector(hv,hv,4,5), a2);
      a3 = dot2f(__builtin_shufflevector(wa,wa,6,7), __builtin_shufflevector(hv,hv,6,7), a3);
    }
    const float gv = (a0 + a1) + (a2 + a3) + xv;
    const float act = fmaf(sigf(sx * gv), m2, m3);

    // quad all-gather: value from quad-lane with gate q is arr[g^q]
    const float A1 = __shfl_xor(act, 1);
    const float A2 = __shfl_xor(act, 2);
    const float A3 = __shfl_xor(A1, 2);
    const float vi = sel4(act, A1, A2, A3, g);
    const float vf = sel4(act, A1, A2, A3, g ^ 1);
    const float vg = sel4(act, A1, A2, A3, g ^ 2);
    const float vo = sel4(act, A1, A2, A3, g ^ 3);

    cst = fmaf(vf, cst, vi * vg);                 // redundant per quad
    const float h = vo * fmaf(sigf(2.f * cst), 2.f, -1.f);
    if (g == 0){
      hbuf[((it + 1) & 1)*256 + j] = (_Float16)h;
      outcat[(size_t)t*512 + dir*256 + j] = h;
    }
    __syncthreads();
  }
}

// ------------------------------ ab ------------------------------------------
__global__ __launch_bounds__(512) void ab_kernel(
    const float* __restrict__ outcat, const float* __restrict__ W1aT,
    const float* __restrict__ W1bT,  const float* __restrict__ b1,
    float* __restrict__ aP, float* __restrict__ bP)
{
  __shared__ float orow[512];
  const int tid = threadIdx.x;
  const int i = blockIdx.x;
  if (tid < 128) ((float4*)orow)[tid] = ((const float4*)(outcat + (size_t)i*512))[tid];
  __syncthreads();
  const int p = tid & 255, sel = tid >> 8;
  const float* W = sel ? W1bT : W1aT;
  float acc = sel ? 0.f : b1[p];
  #pragma unroll 8
  for (int cc = 0; cc < 512; ++cc) acc += orow[cc] * W[cc*256 + p];
  (sel ? bP : aP)[(size_t)i*256 + p] = acc;
}

// ------------------------------ fused MLP -----------------------------------
__global__ __launch_bounds__(256, 2) void mlp_kernel(
    const float* __restrict__ aP, const float* __restrict__ bP,
    const _Float16* __restrict__ W2h, const _Float16* __restrict__ W3h,
    const float* __restrict__ b2, const float* __restrict__ b3p,
    float* __restrict__ outp)
{
  __shared__ _Float16 lds[32768];   // 64KB union: W2 quarter (32KB) / h2 (64KB)
  const int tid = threadIdx.x;
  const int wv  = tid >> 6;
  const int ln  = tid & 31;
  const int hi  = (tid >> 5) & 1;
  const int i     = blockIdx.x >> 2;
  const int jbase = (blockIdx.x & 3) * 128;
  const int j     = jbase + wv*32 + ln;

  f32x16 acc[8];
  #pragma unroll
  for (int nt = 0; nt < 8; ++nt){
    #pragma unroll
    for (int e = 0; e < 16; ++e) acc[nt][e] = 0.f;
  }

  const float* arow = aP + (size_t)i*256;
  const float* brow = bP + (size_t)j*256;

  for (int p = 0; p < 4; ++p){
    if (p) __syncthreads();
    { // stage W2 quarter: rows n=tid, 64 k's, st_16x32 XOR swizzle
      const _Float16* src = W2h + tid*256 + p*64;
      char* dst = (char*)lds + tid*128;
      const int sw = (tid & 7) << 4;
      #pragma unroll
      for (int cc = 0; cc < 8; ++cc){
        f16x8 v = *(const f16x8*)(src + cc*8);
        *(f16x8*)(dst + ((cc*16) ^ sw)) = v;
      }
    }
    __syncthreads();
    #pragma unroll
    for (int ktl = 0; ktl < 4; ++ktl){
      const int kg = (p*4 + ktl)*16 + hi*8;
      float4 a0 = *(const float4*)(arow + kg);
      float4 a1 = *(const float4*)(arow + kg + 4);
      float4 b0 = *(const float4*)(brow + kg);
      float4 b1v = *(const float4*)(brow + kg + 4);
      f16x8 af;
      af[0] = (_Float16)fmaxf(a0.x + b0.x, 0.f);
      af[1] = (_Float16)fmaxf(a0.y + b0.y, 0.f);
      af[2] = (_Float16)fmaxf(a0.z + b0.z, 0.f);
      af[3] = (_Float16)fmaxf(a0.w + b0.w, 0.f);
      af[4] = (_Float16)fmaxf(a1.x + b1v.x, 0.f);
      af[5] = (_Float16)fmaxf(a1.y + b1v.y, 0.f);
      af[6] = (_Float16)fmaxf(a1.z + b1v.z, 0.f);
      af[7] = (_Float16)fmaxf(a1.w + b1v.w, 0.f);
      const int kl2 = (ktl*16 + hi*8) * 2;
      #pragma unroll
      for (int nt = 0; nt < 8; ++nt){
        const int n = nt*32 + ln;
        f16x8 bf = *(const f16x8*)((char*)lds + n*128 + (kl2 ^ ((n & 7) << 4)));
        acc[nt] = __builtin_amdgcn_mfma_f32_32x32x16_f16(af, bf, acc[nt], 0, 0, 0);
      }
    }
  }
  __syncthreads();
  // h2 -> LDS [128 pairs][256 ch] f16, XOR-swizzled per pair-row
  #pragma unroll
  for (int nt = 0; nt < 8; ++nt){
    const int ch = nt*32 + ln;
    const float bb = b2[ch];
    #pragma unroll
    for (int r = 0; r < 16; ++r){
      const int pr = wv*32 + (r & 3) + 8*(r >> 2) + 4*hi;
      const float v = fmaxf(acc[nt][r] + bb, 0.f);
      *(_Float16*)((char*)lds + pr*512 + ((ch*2) ^ ((pr & 7) << 4))) = (_Float16)v;
    }
  }
  __syncthreads();
  // logits
  f32x16 acc2[2];
  #pragma unroll
  for (int nt = 0; nt < 2; ++nt){
    #pragma unroll
    for (int e = 0; e < 16; ++e) acc2[nt][e] = 0.f;
  }
  const int pr = wv*32 + ln;
  const int sw2 = (pr & 7) << 4;
  #pragma unroll
  for (int kt = 0; kt < 16; ++kt){
    const int kb = kt*16 + hi*8;
    f16x8 a2 = *(const f16x8*)((char*)lds + pr*512 + ((kb*2) ^ sw2));
    #pragma unroll
    for (int nt = 0; nt < 2; ++nt){
      const int n = nt*32 + ln;
      f16x8 bf = *(const f16x8*)(W3h + n*256 + kb);
      acc2[nt] = __builtin_amdgcn_mfma_f32_32x32x16_f16(a2, bf, acc2[nt], 0, 0, 0);
    }
  }
  // log_softmax over 50 classes
  const float b30 = b3p[ln], b31 = b3p[32 + ln];
  const bool ok2 = (ln < 18);
  #pragma unroll
  for (int qr = 0; qr < 16; ++qr){
    const int r = (qr & 3) + 8*(qr >> 2) + 4*hi;
    float v0 = acc2[0][qr] + b30;
    float v1 = acc2[1][qr] + b31;
    float m = ok2 ? fmaxf(v0, v1) : v0;
    #pragma unroll
    for (int d = 1; d < 32; d <<= 1) m = fmaxf(m, __shfl_xor(m, d));
    float s = __expf(v0 - m) + (ok2 ? __expf(v1 - m) : 0.f);
    #pragma unroll
    for (int d = 1; d < 32; d <<= 1) s += __shfl_xor(s, d);
    const float lse = m + __logf(s);
    const size_t base = ((size_t)(i*512 + jbase + wv*32 + r)) * 50;
    outp[base + ln] = v0 - lse;
    if (ok2) outp[base + 32 + ln] = v1 - lse;
  }
}

// ------------------------------ launch --------------------------------------
extern "C" void kernel_launch(void* const* d_in, const int* in_sizes, int n_in,
                              void* d_out, int out_size, void* d_ws, size_t ws_size,
                              hipStream_t stream)
{
  const float* x     = (const float*)d_in[0];
  const float* Wih_f = (const float*)d_in[1];
  const float* Whh_f = (const float*)d_in[2];
  const float* bih_f = (const float*)d_in[3];
  const float* bhh_f = (const float*)d_in[4];
  const float* Wih_b = (const float*)d_in[5];
  const float* Whh_b = (const float*)d_in[6];
  const float* bih_b = (const float*)d_in[7];
  const float* bhh_b = (const float*)d_in[8];
  const float* W1    = (const float*)d_in[9];
  const float* b1    = (const float*)d_in[10];
  const float* W2    = (const float*)d_in[11];
  const float* b2    = (const float*)d_in[12];
  const float* W3    = (const float*)d_in[13];
  const float* b3    = (const float*)d_in[14];

  char* ws = (char*)d_ws;
  float*    xb     = (float*)(ws + 0);            // 4,194,304
  float*    outcat = (float*)(ws + 4194304);      // 1,048,576
  float*    aP     = (float*)(ws + 5242880);      //   524,288
  float*    bP     = (float*)(ws + 5767168);      //   524,288
  float*    WihT   = (float*)(ws + 6291456);      // 2,457,600
  float*    W1aT   = (float*)(ws + 8749056);      //   524,288
  float*    W1bT   = (float*)(ws + 9273344);      //   524,288
  _Float16* W2h    = (_Float16*)(ws + 9797632);   //   131,072
  _Float16* W3h    = (_Float16*)(ws + 9928704);   //    32,768
  float*    b3p    = (float*)(ws + 9961472);      //       256

  if (ws_size < 9963808) return;   // leaves d_out poisoned -> clean failure

  // lstm needs 132,096 B of dynamic LDS (>64 KB static limit)
  (void)hipFuncSetAttribute((const void*)lstm_kernel,
                            hipFuncAttributeMaxDynamicSharedMemorySize, 132096);

  prep_kernel<<<3745, 256, 0, stream>>>(Wih_f, Wih_b, W1, W2, W3, b3,
                                        WihT, W1aT, W1bT, W2h, W3h, b3p);
  xb_kernel<<<256, 256, 0, stream>>>(x, WihT, bih_f, bhh_f, bih_b, bhh_b, xb);
  lstm_kernel<<<2, 1024, 132096, stream>>>(Whh_f, Whh_b, xb, outcat);
  ab_kernel<<<512, 512, 0, stream>>>(outcat, W1aT, W1bT, b1, aP, bP);
  mlp_kernel<<<2048, 256, 0, stream>>>(aP, bP, W2h, W3h, b2, b3p, (float*)d_out);
}

// Round 8
// 1326.972 us; speedup vs baseline: 1.4182x; 1.1903x over previous
//
#include <hip/hip_runtime.h>
#include <hip/hip_bf16.h>
#include <hip/hip_fp16.h>

// ---------------------------------------------------------------------------
// BiLSTM (N=512, D_IN=300, H=256) + pairwise 3-layer MLP (4H->H->H->50)
// + log_softmax, on MI355X.
//
//   lstm (round-8): one block/direction, 512 threads, thread=(gate g, jj)
//   owns rows g*256+jj and g*256+jj+128. amdgpu_waves_per_eu(2,2) -> 256-reg
//   budget/wave -> 192 f16x2 weights in ARCH VGPRs (copy-free v_dot2_f32_f16).
//   k[192,256) weights in 128 KB XOR-swizzled LDS. h via LDS uniform b128
//   broadcast; quad __shfl_xor gate exchange; ONE barrier/step.
//   (r4/r6/r7 lesson: at 1024 thr the unified-file budget is 128/wave and
//   big arrays go to AGPRs; 512 thr @ 2 waves/SIMD is the only config where
//   192 weight regs fit in arch VGPRs.)
// ---------------------------------------------------------------------------

typedef _Float16 f16x2 __attribute__((ext_vector_type(2)));
typedef _Float16 f16x8 __attribute__((ext_vector_type(8)));
typedef float    f32x16 __attribute__((ext_vector_type(16)));

__device__ __forceinline__ float sigf(float x){ return 1.f/(1.f + __expf(-x)); }
// Packed dot on VGPR operands (weights are arch-VGPR resident by design).
__device__ __forceinline__ float dot2f(f16x2 a, f16x2 b, float c){
  float d;
  asm("v_dot2_f32_f16 %0, %1, %2, %3" : "=v"(d) : "v"(a), "v"(b), "v"(c));
  return d;
}
__device__ __forceinline__ float sel4(float a0, float a1, float a2, float a3, int idx){
  float lo = (idx & 1) ? a1 : a0;
  float hi = (idx & 1) ? a3 : a2;
  return (idx & 2) ? hi : lo;
}

// ------------------------------ prep ---------------------------------------
__global__ __launch_bounds__(256) void prep_kernel(
    const float* __restrict__ Wih_f, const float* __restrict__ Wih_b,
    const float* __restrict__ W1,    const float* __restrict__ W2,
    const float* __restrict__ W3,    const float* __restrict__ b3,
    float* __restrict__ WihT, float* __restrict__ W1aT, float* __restrict__ W1bT,
    _Float16* __restrict__ W2h, _Float16* __restrict__ W3h,
    float* __restrict__ b3p)
{
  int idx = blockIdx.x * 256 + threadIdx.x;
  if (idx < 614400){                     // WihT[d][c][r] = Wih_d[r][c]
    int d = idx / 307200, r2 = idx % 307200;
    int cc = r2 / 1024, rr = r2 % 1024;
    const float* src = d ? Wih_b : Wih_f;
    WihT[idx] = src[rr*300 + cc];
    return;
  }
  idx -= 614400;
  if (idx < 262144){                     // W1aT[c][p]=W1[p][c]; W1bT[c][p]=W1[p][512+c]
    int sel = idx / 131072, r2 = idx % 131072;
    int cc = r2 / 256, pp = r2 % 256;
    float v = W1[pp*1024 + sel*512 + cc];
    (sel ? W1bT : W1aT)[r2] = v;
    return;
  }
  idx -= 262144;
  if (idx < 65536){ W2h[idx] = (_Float16)W2[idx]; return; }
  idx -= 65536;
  if (idx < 16384){                      // W3h padded to [64][256]
    int n = idx >> 8, k = idx & 255;
    W3h[idx] = (n < 50) ? (_Float16)W3[n*256 + k] : (_Float16)0.f;
    return;
  }
  idx -= 16384;
  if (idx < 64){ b3p[idx] = (idx < 50) ? b3[idx] : 0.f; return; }
}

// ------------------------------ xb ------------------------------------------
__global__ __launch_bounds__(256) void xb_kernel(
    const float* __restrict__ x, const float* __restrict__ WihT,
    const float* __restrict__ bih_f, const float* __restrict__ bhh_f,
    const float* __restrict__ bih_b, const float* __restrict__ bhh_b,
    float* __restrict__ xb)
{
  const int tid = threadIdx.x;
  const int dir = blockIdx.x >> 7;
  const int t0  = (blockIdx.x & 127) * 4;
  __shared__ float xs[4][304];
  #pragma unroll
  for (int tt = 0; tt < 4; ++tt)
    if (tid < 75) ((float4*)xs[tt])[tid] = ((const float4*)(x + (size_t)(t0+tt)*300))[tid];
  __syncthreads();
  const float* W = WihT + dir*307200;
  float acc[4][4];
  #pragma unroll
  for (int r = 0; r < 4; ++r){
    #pragma unroll
    for (int tt = 0; tt < 4; ++tt) acc[r][tt] = 0.f;
  }
  for (int c = 0; c < 300; ++c){
    float x0 = xs[0][c], x1 = xs[1][c], x2 = xs[2][c], x3 = xs[3][c];
    #pragma unroll
    for (int r = 0; r < 4; ++r){
      float wv = W[c*1024 + r*256 + tid];
      acc[r][0] += wv*x0; acc[r][1] += wv*x1; acc[r][2] += wv*x2; acc[r][3] += wv*x3;
    }
  }
  const float* bih = dir ? bih_b : bih_f;
  const float* bhh = dir ? bhh_b : bhh_f;
  float* xbd = xb + (size_t)dir*512*1024;
  #pragma unroll
  for (int r = 0; r < 4; ++r){
    int R = r*256 + tid;
    float bias = bih[R] + bhh[R];
    #pragma unroll
    for (int tt = 0; tt < 4; ++tt)
      xbd[(size_t)(t0+tt)*1024 + R] = acc[r][tt] + bias;
  }
}

// ------------------------------ lstm ----------------------------------------
__global__ __launch_bounds__(512)
__attribute__((amdgpu_waves_per_eu(2, 2)))
void lstm_kernel(
    const float* __restrict__ Whh_f, const float* __restrict__ Whh_b,
    const float* __restrict__ xb, float* __restrict__ outcat)
{
  extern __shared__ char smem[];
  _Float16* wlds = (_Float16*)smem;              // [1024 rows][64 k] swz = 128 KB
  _Float16* hbuf = (_Float16*)(smem + 131072);   // [2][256] = 1 KB

  const int tid = threadIdx.x;
  const int dir = blockIdx.x;
  const int g   = tid & 3;
  const int jj  = tid >> 2;             // [0,128)
  const int rA  = g*256 + jj;
  const int rB  = rA + 128;
  const float* Whh = dir ? Whh_b : Whh_f;

  // ---- k[0,192): 2 x 96 f16x2 in arch VGPRs (256-reg budget @ 2 waves/EU)
  f16x2 wA[96], wB[96];
  {
    const float4* pa = (const float4*)(Whh + (size_t)rA*256);
    const float4* pb = (const float4*)(Whh + (size_t)rB*256);
    #pragma unroll
    for (int q = 0; q < 48; ++q){
      float4 va = pa[q];
      f16x2 t0, t1;
      t0[0]=(_Float16)va.x; t0[1]=(_Float16)va.y;
      t1[0]=(_Float16)va.z; t1[1]=(_Float16)va.w;
      wA[2*q] = t0; wA[2*q+1] = t1;
      float4 vb = pb[q];
      t0[0]=(_Float16)vb.x; t0[1]=(_Float16)vb.y;
      t1[0]=(_Float16)vb.z; t1[1]=(_Float16)vb.w;
      wB[2*q] = t0; wB[2*q+1] = t1;
    }
  }
  // ---- k[192,256): LDS, XOR-swizzled (row stride 128 B); rB&7 == rA&7
  const int sw = (rA & 7) << 4;
  {
    const float4* pa = (const float4*)(Whh + (size_t)rA*256);
    const float4* pb = (const float4*)(Whh + (size_t)rB*256);
    #pragma unroll
    for (int cc = 0; cc < 8; ++cc){
      float4 v0 = pa[48 + cc*2];
      float4 v1 = pa[48 + cc*2 + 1];
      f16x8 o;
      o[0]=(_Float16)v0.x; o[1]=(_Float16)v0.y; o[2]=(_Float16)v0.z; o[3]=(_Float16)v0.w;
      o[4]=(_Float16)v1.x; o[5]=(_Float16)v1.y; o[6]=(_Float16)v1.z; o[7]=(_Float16)v1.w;
      *(f16x8*)((char*)wlds + rA*128 + ((cc*16) ^ sw)) = o;
      v0 = pb[48 + cc*2];
      v1 = pb[48 + cc*2 + 1];
      o[0]=(_Float16)v0.x; o[1]=(_Float16)v0.y; o[2]=(_Float16)v0.z; o[3]=(_Float16)v0.w;
      o[4]=(_Float16)v1.x; o[5]=(_Float16)v1.y; o[6]=(_Float16)v1.z; o[7]=(_Float16)v1.w;
      *(f16x8*)((char*)wlds + rB*128 + ((cc*16) ^ sw)) = o;
    }
  }
  if (tid < 32) ((f16x8*)hbuf)[tid] = (f16x8)(_Float16)0.f;   // h_{-1} = 0
  __syncthreads();

  // gate 2 (cell) uses tanh = 2*sig(2x)-1; others sigmoid
  const float sx = (g==2) ? 2.f : 1.f;
  const float m2 = (g==2) ? 2.f : 1.f;
  const float m3 = (g==2) ? -1.f : 0.f;

  const float* xbd = xb + (size_t)dir*512*1024;
  float c0 = 0.f, c1 = 0.f;

  for (int it = 0; it < 512; ++it){
    const int t = dir ? (511 - it) : it;
    const float xv0 = xbd[(size_t)t*1024 + rA];   // issued early, used late
    const float xv1 = xbd[(size_t)t*1024 + rB];
    const f16x8* hb = (const f16x8*)(hbuf + (it & 1)*256);

    float a0=0.f, a1=0.f, a2=0.f, a3=0.f;
    float b0=0.f, b1=0.f, b2=0.f, b3=0.f;
    #pragma unroll
    for (int cc = 0; cc < 24; ++cc){              // k[0,192): VGPR weights
      f16x8 hv = hb[cc];                          // uniform -> LDS broadcast
      f16x2 h0 = __builtin_shufflevector(hv, hv, 0, 1);
      f16x2 h1 = __builtin_shufflevector(hv, hv, 2, 3);
      f16x2 h2 = __builtin_shufflevector(hv, hv, 4, 5);
      f16x2 h3 = __builtin_shufflevector(hv, hv, 6, 7);
      a0 = dot2f(wA[4*cc+0], h0, a0); a1 = dot2f(wA[4*cc+1], h1, a1);
      a2 = dot2f(wA[4*cc+2], h2, a2); a3 = dot2f(wA[4*cc+3], h3, a3);
      b0 = dot2f(wB[4*cc+0], h0, b0); b1 = dot2f(wB[4*cc+1], h1, b1);
      b2 = dot2f(wB[4*cc+2], h2, b2); b3 = dot2f(wB[4*cc+3], h3, b3);
    }
    #pragma unroll
    for (int cc = 0; cc < 8; ++cc){               // k[192,256): LDS weights
      f16x8 hv = hb[24+cc];
      f16x8 wa = *(const f16x8*)((char*)wlds + rA*128 + ((cc*16) ^ sw));
      f16x8 wb = *(const f16x8*)((char*)wlds + rB*128 + ((cc*16) ^ sw));
      a0 = dot2f(__builtin_shufflevector(wa,wa,0,1), __builtin_shufflevector(hv,hv,0,1), a0);
      a1 = dot2f(__builtin_shufflevector(wa,wa,2,3), __builtin_shufflevector(hv,hv,2,3), a1);
      a2 = dot2f(__builtin_shufflevector(wa,wa,4,5), __builtin_shufflevector(hv,hv,4,5), a2);
      a3 = dot2f(__builtin_shufflevector(wa,wa,6,7), __builtin_shufflevector(hv,hv,6,7), a3);
      b0 = dot2f(__builtin_shufflevector(wb,wb,0,1), __builtin_shufflevector(hv,hv,0,1), b0);
      b1 = dot2f(__builtin_shufflevector(wb,wb,2,3), __builtin_shufflevector(hv,hv,2,3), b1);
      b2 = dot2f(__builtin_shufflevector(wb,wb,4,5), __builtin_shufflevector(hv,hv,4,5), b2);
      b3 = dot2f(__builtin_shufflevector(wb,wb,6,7), __builtin_shufflevector(hv,hv,6,7), b3);
    }
    const float gA = (a0 + a1) + (a2 + a3) + xv0;
    const float gB = (b0 + b1) + (b2 + b3) + xv1;
    const float actA = fmaf(sigf(sx * gA), m2, m3);
    const float actB = fmaf(sigf(sx * gB), m2, m3);

    // quad all-gather: value from quad-lane with gate q is arr[g^q]
    const float A1 = __shfl_xor(actA, 1);
    const float A2 = __shfl_xor(actA, 2);
    const float A3 = __shfl_xor(A1, 2);
    const float B1 = __shfl_xor(actB, 1);
    const float B2 = __shfl_xor(actB, 2);
    const float B3 = __shfl_xor(B1, 2);
    const float viA = sel4(actA, A1, A2, A3, g);
    const float vfA = sel4(actA, A1, A2, A3, g ^ 1);
    const float vgA = sel4(actA, A1, A2, A3, g ^ 2);
    const float voA = sel4(actA, A1, A2, A3, g ^ 3);
    const float viB = sel4(actB, B1, B2, B3, g);
    const float vfB = sel4(actB, B1, B2, B3, g ^ 1);
    const float vgB = sel4(actB, B1, B2, B3, g ^ 2);
    const float voB = sel4(actB, B1, B2, B3, g ^ 3);

    c0 = fmaf(vfA, c0, viA * vgA);                // redundant per quad
    c1 = fmaf(vfB, c1, viB * vgB);
    const float h0 = voA * fmaf(sigf(2.f * c0), 2.f, -1.f);
    const float h1 = voB * fmaf(sigf(2.f * c1), 2.f, -1.f);

    if (g == 0){
      _Float16* hn = hbuf + ((it + 1) & 1)*256;
      hn[jj]       = (_Float16)h0;
      hn[jj + 128] = (_Float16)h1;
      outcat[(size_t)t*512 + dir*256 + jj]       = h0;
      outcat[(size_t)t*512 + dir*256 + jj + 128] = h1;
    }
    __syncthreads();
  }
}

// ------------------------------ ab ------------------------------------------
__global__ __launch_bounds__(512) void ab_kernel(
    const float* __restrict__ outcat, const float* __restrict__ W1aT,
    const float* __restrict__ W1bT,  const float* __restrict__ b1,
    float* __restrict__ aP, float* __restrict__ bP)
{
  __shared__ float orow[512];
  const int tid = threadIdx.x;
  const int i = blockIdx.x;
  if (tid < 128) ((float4*)orow)[tid] = ((const float4*)(outcat + (size_t)i*512))[tid];
  __syncthreads();
  const int p = tid & 255, sel = tid >> 8;
  const float* W = sel ? W1bT : W1aT;
  float acc = sel ? 0.f : b1[p];
  #pragma unroll 8
  for (int cc = 0; cc < 512; ++cc) acc += orow[cc] * W[cc*256 + p];
  (sel ? bP : aP)[(size_t)i*256 + p] = acc;
}

// ------------------------------ fused MLP -----------------------------------
__global__ __launch_bounds__(256, 2) void mlp_kernel(
    const float* __restrict__ aP, const float* __restrict__ bP,
    const _Float16* __restrict__ W2h, const _Float16* __restrict__ W3h,
    const float* __restrict__ b2, const float* __restrict__ b3p,
    float* __restrict__ outp)
{
  __shared__ _Float16 lds[32768];   // 64KB union: W2 quarter (32KB) / h2 (64KB)
  const int tid = threadIdx.x;
  const int wv  = tid >> 6;
  const int ln  = tid & 31;
  const int hi  = (tid >> 5) & 1;
  const int i     = blockIdx.x >> 2;
  const int jbase = (blockIdx.x & 3) * 128;
  const int j     = jbase + wv*32 + ln;

  f32x16 acc[8];
  #pragma unroll
  for (int nt = 0; nt < 8; ++nt){
    #pragma unroll
    for (int e = 0; e < 16; ++e) acc[nt][e] = 0.f;
  }

  const float* arow = aP + (size_t)i*256;
  const float* brow = bP + (size_t)j*256;

  for (int p = 0; p < 4; ++p){
    if (p) __syncthreads();
    { // stage W2 quarter: rows n=tid, 64 k's, st_16x32 XOR swizzle
      const _Float16* src = W2h + tid*256 + p*64;
      char* dst = (char*)lds + tid*128;
      const int sw = (tid & 7) << 4;
      #pragma unroll
      for (int cc = 0; cc < 8; ++cc){
        f16x8 v = *(const f16x8*)(src + cc*8);
        *(f16x8*)(dst + ((cc*16) ^ sw)) = v;
      }
    }
    __syncthreads();
    #pragma unroll
    for (int ktl = 0; ktl < 4; ++ktl){
      const int kg = (p*4 + ktl)*16 + hi*8;
      float4 a0 = *(const float4*)(arow + kg);
      float4 a1 = *(const float4*)(arow + kg + 4);
      float4 b0 = *(const float4*)(brow + kg);
      float4 b1v = *(const float4*)(brow + kg + 4);
      f16x8 af;
      af[0] = (_Float16)fmaxf(a0.x + b0.x, 0.f);
      af[1] = (_Float16)fmaxf(a0.y + b0.y, 0.f);
      af[2] = (_Float16)fmaxf(a0.z + b0.z, 0.f);
      af[3] = (_Float16)fmaxf(a0.w + b0.w, 0.f);
      af[4] = (_Float16)fmaxf(a1.x + b1v.x, 0.f);
      af[5] = (_Float16)fmaxf(a1.y + b1v.y, 0.f);
      af[6] = (_Float16)fmaxf(a1.z + b1v.z, 0.f);
      af[7] = (_Float16)fmaxf(a1.w + b1v.w, 0.f);
      const int kl2 = (ktl*16 + hi*8) * 2;
      #pragma unroll
      for (int nt = 0; nt < 8; ++nt){
        const int n = nt*32 + ln;
        f16x8 bf = *(const f16x8*)((char*)lds + n*128 + (kl2 ^ ((n & 7) << 4)));
        acc[nt] = __builtin_amdgcn_mfma_f32_32x32x16_f16(af, bf, acc[nt], 0, 0, 0);
      }
    }
  }
  __syncthreads();
  // h2 -> LDS [128 pairs][256 ch] f16, XOR-swizzled per pair-row
  #pragma unroll
  for (int nt = 0; nt < 8; ++nt){
    const int ch = nt*32 + ln;
    const float bb = b2[ch];
    #pragma unroll
    for (int r = 0; r < 16; ++r){
      const int pr = wv*32 + (r & 3) + 8*(r >> 2) + 4*hi;
      const float v = fmaxf(acc[nt][r] + bb, 0.f);
      *(_Float16*)((char*)lds + pr*512 + ((ch*2) ^ ((pr & 7) << 4))) = (_Float16)v;
    }
  }
  __syncthreads();
  // logits
  f32x16 acc2[2];
  #pragma unroll
  for (int nt = 0; nt < 2; ++nt){
    #pragma unroll
    for (int e = 0; e < 16; ++e) acc2[nt][e] = 0.f;
  }
  const int pr = wv*32 + ln;
  const int sw2 = (pr & 7) << 4;
  #pragma unroll
  for (int kt = 0; kt < 16; ++kt){
    const int kb = kt*16 + hi*8;
    f16x8 a2 = *(const f16x8*)((char*)lds + pr*512 + ((kb*2) ^ sw2));
    #pragma unroll
    for (int nt = 0; nt < 2; ++nt){
      const int n = nt*32 + ln;
      f16x8 bf = *(const f16x8*)(W3h + n*256 + kb);
      acc2[nt] = __builtin_amdgcn_mfma_f32_32x32x16_f16(a2, bf, acc2[nt], 0, 0, 0);
    }
  }
  // log_softmax over 50 classes
  const float b30 = b3p[ln], b31 = b3p[32 + ln];
  const bool ok2 = (ln < 18);
  #pragma unroll
  for (int qr = 0; qr < 16; ++qr){
    const int r = (qr & 3) + 8*(qr >> 2) + 4*hi;
    float v0 = acc2[0][qr] + b30;
    float v1 = acc2[1][qr] + b31;
    float m = ok2 ? fmaxf(v0, v1) : v0;
    #pragma unroll
    for (int d = 1; d < 32; d <<= 1) m = fmaxf(m, __shfl_xor(m, d));
    float s = __expf(v0 - m) + (ok2 ? __expf(v1 - m) : 0.f);
    #pragma unroll
    for (int d = 1; d < 32; d <<= 1) s += __shfl_xor(s, d);
    const float lse = m + __logf(s);
    const size_t base = ((size_t)(i*512 + jbase + wv*32 + r)) * 50;
    outp[base + ln] = v0 - lse;
    if (ok2) outp[base + 32 + ln] = v1 - lse;
  }
}

// ------------------------------ launch --------------------------------------
extern "C" void kernel_launch(void* const* d_in, const int* in_sizes, int n_in,
                              void* d_out, int out_size, void* d_ws, size_t ws_size,
                              hipStream_t stream)
{
  const float* x     = (const float*)d_in[0];
  const float* Wih_f = (const float*)d_in[1];
  const float* Whh_f = (const float*)d_in[2];
  const float* bih_f = (const float*)d_in[3];
  const float* bhh_f = (const float*)d_in[4];
  const float* Wih_b = (const float*)d_in[5];
  const float* Whh_b = (const float*)d_in[6];
  const float* bih_b = (const float*)d_in[7];
  const float* bhh_b = (const float*)d_in[8];
  const float* W1    = (const float*)d_in[9];
  const float* b1    = (const float*)d_in[10];
  const float* W2    = (const float*)d_in[11];
  const float* b2    = (const float*)d_in[12];
  const float* W3    = (const float*)d_in[13];
  const float* b3    = (const float*)d_in[14];

  char* ws = (char*)d_ws;
  float*    xb     = (float*)(ws + 0);            // 4,194,304
  float*    outcat = (float*)(ws + 4194304);      // 1,048,576
  float*    aP     = (float*)(ws + 5242880);      //   524,288
  float*    bP     = (float*)(ws + 5767168);      //   524,288
  float*    WihT   = (float*)(ws + 6291456);      // 2,457,600
  float*    W1aT   = (float*)(ws + 8749056);      //   524,288
  float*    W1bT   = (float*)(ws + 9273344);      //   524,288
  _Float16* W2h    = (_Float16*)(ws + 9797632);   //   131,072
  _Float16* W3h    = (_Float16*)(ws + 9928704);   //    32,768
  float*    b3p    = (float*)(ws + 9961472);      //       256

  if (ws_size < 9963808) return;   // leaves d_out poisoned -> clean failure

  // lstm needs 132,096 B of dynamic LDS (>64 KB static limit)
  (void)hipFuncSetAttribute((const void*)lstm_kernel,
                            hipFuncAttributeMaxDynamicSharedMemorySize, 132096);

  prep_kernel<<<3745, 256, 0, stream>>>(Wih_f, Wih_b, W1, W2, W3, b3,
                                        WihT, W1aT, W1bT, W2h, W3h, b3p);
  xb_kernel<<<256, 256, 0, stream>>>(x, WihT, bih_f, bhh_f, bih_b, bhh_b, xb);
  lstm_kernel<<<2, 512, 132096, stream>>>(Whh_f, Whh_b, xb, outcat);
  ab_kernel<<<512, 512, 0, stream>>>(outcat, W1aT, W1bT, b1, aP, bP);
  mlp_kernel<<<2048, 256, 0, stream>>>(aP, bP, W2h, W3h, b2, b3p, (float*)d_out);
}

// Round 9
// 1281.901 us; speedup vs baseline: 1.4681x; 1.0352x over previous
//
#include <hip/hip_runtime.h>
#include <hip/hip_bf16.h>
#include <hip/hip_fp16.h>

// ---------------------------------------------------------------------------
// BiLSTM (N=512, D_IN=300, H=256) + pairwise 3-layer MLP (4H->H->H->50)
// + log_softmax, on MI355X.
//
//   lstm (round-9): r8 structure (one block/direction, 512 threads,
//   thread=(gate g, jj) owns rows g*256+jj and +128; k[0,192) weights in
//   192 f16x2 regs (AGPR-resident by allocator choice), k[192,256) in
//   128 KB XOR-swizzled LDS; h via LDS uniform b128; quad __shfl_xor gate
//   exchange; ONE barrier/step) with ONE change: dot2f uses the compiler
//   path (builtin fdot2 / fma fallback) instead of "v"-constrained asm.
//   r2-r8 evidence: gfx950 VALU consumes AGPR-resident weights directly
//   (~2 instr/dot2); the asm "v" constraint forced v_accvgpr_read copies
//   (~2.9 instr/dot2). Cooperate with the allocator, don't fight it.
// ---------------------------------------------------------------------------

typedef _Float16 f16x2 __attribute__((ext_vector_type(2)));
typedef _Float16 f16x8 __attribute__((ext_vector_type(8)));
typedef float    f32x16 __attribute__((ext_vector_type(16)));

__device__ __forceinline__ float sigf(float x){ return 1.f/(1.f + __expf(-x)); }
// Compiler-chosen packed dot: builtin if present, else fma fallback
// (lowers to v_fma_mix pairs / v_dot2 that can source AGPRs directly).
__device__ __forceinline__ float dot2f(f16x2 a, f16x2 b, float c){
#if __has_builtin(__builtin_amdgcn_fdot2)
  return __builtin_amdgcn_fdot2(a, b, c, false);
#else
  return c + (float)a[0]*(float)b[0] + (float)a[1]*(float)b[1];
#endif
}
__device__ __forceinline__ float sel4(float a0, float a1, float a2, float a3, int idx){
  float lo = (idx & 1) ? a1 : a0;
  float hi = (idx & 1) ? a3 : a2;
  return (idx & 2) ? hi : lo;
}

// ------------------------------ prep ---------------------------------------
__global__ __launch_bounds__(256) void prep_kernel(
    const float* __restrict__ Wih_f, const float* __restrict__ Wih_b,
    const float* __restrict__ W1,    const float* __restrict__ W2,
    const float* __restrict__ W3,    const float* __restrict__ b3,
    float* __restrict__ WihT, float* __restrict__ W1aT, float* __restrict__ W1bT,
    _Float16* __restrict__ W2h, _Float16* __restrict__ W3h,
    float* __restrict__ b3p)
{
  int idx = blockIdx.x * 256 + threadIdx.x;
  if (idx < 614400){                     // WihT[d][c][r] = Wih_d[r][c]
    int d = idx / 307200, r2 = idx % 307200;
    int cc = r2 / 1024, rr = r2 % 1024;
    const float* src = d ? Wih_b : Wih_f;
    WihT[idx] = src[rr*300 + cc];
    return;
  }
  idx -= 614400;
  if (idx < 262144){                     // W1aT[c][p]=W1[p][c]; W1bT[c][p]=W1[p][512+c]
    int sel = idx / 131072, r2 = idx % 131072;
    int cc = r2 / 256, pp = r2 % 256;
    float v = W1[pp*1024 + sel*512 + cc];
    (sel ? W1bT : W1aT)[r2] = v;
    return;
  }
  idx -= 262144;
  if (idx < 65536){ W2h[idx] = (_Float16)W2[idx]; return; }
  idx -= 65536;
  if (idx < 16384){                      // W3h padded to [64][256]
    int n = idx >> 8, k = idx & 255;
    W3h[idx] = (n < 50) ? (_Float16)W3[n*256 + k] : (_Float16)0.f;
    return;
  }
  idx -= 16384;
  if (idx < 64){ b3p[idx] = (idx < 50) ? b3[idx] : 0.f; return; }
}

// ------------------------------ xb ------------------------------------------
__global__ __launch_bounds__(256) void xb_kernel(
    const float* __restrict__ x, const float* __restrict__ WihT,
    const float* __restrict__ bih_f, const float* __restrict__ bhh_f,
    const float* __restrict__ bih_b, const float* __restrict__ bhh_b,
    float* __restrict__ xb)
{
  const int tid = threadIdx.x;
  const int dir = blockIdx.x >> 7;
  const int t0  = (blockIdx.x & 127) * 4;
  __shared__ float xs[4][304];
  #pragma unroll
  for (int tt = 0; tt < 4; ++tt)
    if (tid < 75) ((float4*)xs[tt])[tid] = ((const float4*)(x + (size_t)(t0+tt)*300))[tid];
  __syncthreads();
  const float* W = WihT + dir*307200;
  float acc[4][4];
  #pragma unroll
  for (int r = 0; r < 4; ++r){
    #pragma unroll
    for (int tt = 0; tt < 4; ++tt) acc[r][tt] = 0.f;
  }
  for (int c = 0; c < 300; ++c){
    float x0 = xs[0][c], x1 = xs[1][c], x2 = xs[2][c], x3 = xs[3][c];
    #pragma unroll
    for (int r = 0; r < 4; ++r){
      float wv = W[c*1024 + r*256 + tid];
      acc[r][0] += wv*x0; acc[r][1] += wv*x1; acc[r][2] += wv*x2; acc[r][3] += wv*x3;
    }
  }
  const float* bih = dir ? bih_b : bih_f;
  const float* bhh = dir ? bhh_b : bhh_f;
  float* xbd = xb + (size_t)dir*512*1024;
  #pragma unroll
  for (int r = 0; r < 4; ++r){
    int R = r*256 + tid;
    float bias = bih[R] + bhh[R];
    #pragma unroll
    for (int tt = 0; tt < 4; ++tt)
      xbd[(size_t)(t0+tt)*1024 + R] = acc[r][tt] + bias;
  }
}

// ------------------------------ lstm ----------------------------------------
__global__ __launch_bounds__(512)
__attribute__((amdgpu_waves_per_eu(2, 2)))
void lstm_kernel(
    const float* __restrict__ Whh_f, const float* __restrict__ Whh_b,
    const float* __restrict__ xb, float* __restrict__ outcat)
{
  extern __shared__ char smem[];
  _Float16* wlds = (_Float16*)smem;              // [1024 rows][64 k] swz = 128 KB
  _Float16* hbuf = (_Float16*)(smem + 131072);   // [2][256] = 1 KB

  const int tid = threadIdx.x;
  const int dir = blockIdx.x;
  const int g   = tid & 3;
  const int jj  = tid >> 2;             // [0,128)
  const int rA  = g*256 + jj;
  const int rB  = rA + 128;
  const float* Whh = dir ? Whh_b : Whh_f;

  // ---- k[0,192): 2 x 96 f16x2 register-resident (AGPR-friendly)
  f16x2 wA[96], wB[96];
  {
    const float4* pa = (const float4*)(Whh + (size_t)rA*256);
    const float4* pb = (const float4*)(Whh + (size_t)rB*256);
    #pragma unroll
    for (int q = 0; q < 48; ++q){
      float4 va = pa[q];
      f16x2 t0, t1;
      t0[0]=(_Float16)va.x; t0[1]=(_Float16)va.y;
      t1[0]=(_Float16)va.z; t1[1]=(_Float16)va.w;
      wA[2*q] = t0; wA[2*q+1] = t1;
      float4 vb = pb[q];
      t0[0]=(_Float16)vb.x; t0[1]=(_Float16)vb.y;
      t1[0]=(_Float16)vb.z; t1[1]=(_Float16)vb.w;
      wB[2*q] = t0; wB[2*q+1] = t1;
    }
  }
  // ---- k[192,256): LDS, XOR-swizzled (row stride 128 B); rB&7 == rA&7
  const int sw = (rA & 7) << 4;
  {
    const float4* pa = (const float4*)(Whh + (size_t)rA*256);
    const float4* pb = (const float4*)(Whh + (size_t)rB*256);
    #pragma unroll
    for (int cc = 0; cc < 8; ++cc){
      float4 v0 = pa[48 + cc*2];
      float4 v1 = pa[48 + cc*2 + 1];
      f16x8 o;
      o[0]=(_Float16)v0.x; o[1]=(_Float16)v0.y; o[2]=(_Float16)v0.z; o[3]=(_Float16)v0.w;
      o[4]=(_Float16)v1.x; o[5]=(_Float16)v1.y; o[6]=(_Float16)v1.z; o[7]=(_Float16)v1.w;
      *(f16x8*)((char*)wlds + rA*128 + ((cc*16) ^ sw)) = o;
      v0 = pb[48 + cc*2];
      v1 = pb[48 + cc*2 + 1];
      o[0]=(_Float16)v0.x; o[1]=(_Float16)v0.y; o[2]=(_Float16)v0.z; o[3]=(_Float16)v0.w;
      o[4]=(_Float16)v1.x; o[5]=(_Float16)v1.y; o[6]=(_Float16)v1.z; o[7]=(_Float16)v1.w;
      *(f16x8*)((char*)wlds + rB*128 + ((cc*16) ^ sw)) = o;
    }
  }
  if (tid < 32) ((f16x8*)hbuf)[tid] = (f16x8)(_Float16)0.f;   // h_{-1} = 0
  __syncthreads();

  // gate 2 (cell) uses tanh = 2*sig(2x)-1; others sigmoid
  const float sx = (g==2) ? 2.f : 1.f;
  const float m2 = (g==2) ? 2.f : 1.f;
  const float m3 = (g==2) ? -1.f : 0.f;

  const float* xbd = xb + (size_t)dir*512*1024;
  float c0 = 0.f, c1 = 0.f;

  for (int it = 0; it < 512; ++it){
    const int t = dir ? (511 - it) : it;
    const float xv0 = xbd[(size_t)t*1024 + rA];   // issued early, used late
    const float xv1 = xbd[(size_t)t*1024 + rB];
    const f16x8* hb = (const f16x8*)(hbuf + (it & 1)*256);

    float a0=0.f, a1=0.f, a2=0.f, a3=0.f;
    float b0=0.f, b1=0.f, b2=0.f, b3=0.f;
    #pragma unroll
    for (int cc = 0; cc < 24; ++cc){              // k[0,192): reg weights
      f16x8 hv = hb[cc];                          // uniform -> LDS broadcast
      f16x2 h0 = __builtin_shufflevector(hv, hv, 0, 1);
      f16x2 h1 = __builtin_shufflevector(hv, hv, 2, 3);
      f16x2 h2 = __builtin_shufflevector(hv, hv, 4, 5);
      f16x2 h3 = __builtin_shufflevector(hv, hv, 6, 7);
      a0 = dot2f(wA[4*cc+0], h0, a0); a1 = dot2f(wA[4*cc+1], h1, a1);
      a2 = dot2f(wA[4*cc+2], h2, a2); a3 = dot2f(wA[4*cc+3], h3, a3);
      b0 = dot2f(wB[4*cc+0], h0, b0); b1 = dot2f(wB[4*cc+1], h1, b1);
      b2 = dot2f(wB[4*cc+2], h2, b2); b3 = dot2f(wB[4*cc+3], h3, b3);
    }
    #pragma unroll
    for (int cc = 0; cc < 8; ++cc){               // k[192,256): LDS weights
      f16x8 hv = hb[24+cc];
      f16x8 wa = *(const f16x8*)((char*)wlds + rA*128 + ((cc*16) ^ sw));
      f16x8 wb = *(const f16x8*)((char*)wlds + rB*128 + ((cc*16) ^ sw));
      a0 = dot2f(__builtin_shufflevector(wa,wa,0,1), __builtin_shufflevector(hv,hv,0,1), a0);
      a1 = dot2f(__builtin_shufflevector(wa,wa,2,3), __builtin_shufflevector(hv,hv,2,3), a1);
      a2 = dot2f(__builtin_shufflevector(wa,wa,4,5), __builtin_shufflevector(hv,hv,4,5), a2);
      a3 = dot2f(__builtin_shufflevector(wa,wa,6,7), __builtin_shufflevector(hv,hv,6,7), a3);
      b0 = dot2f(__builtin_shufflevector(wb,wb,0,1), __builtin_shufflevector(hv,hv,0,1), b0);
      b1 = dot2f(__builtin_shufflevector(wb,wb,2,3), __builtin_shufflevector(hv,hv,2,3), b1);
      b2 = dot2f(__builtin_shufflevector(wb,wb,4,5), __builtin_shufflevector(hv,hv,4,5), b2);
      b3 = dot2f(__builtin_shufflevector(wb,wb,6,7), __builtin_shufflevector(hv,hv,6,7), b3);
    }
    const float gA = (a0 + a1) + (a2 + a3) + xv0;
    const float gB = (b0 + b1) + (b2 + b3) + xv1;
    const float actA = fmaf(sigf(sx * gA), m2, m3);
    const float actB = fmaf(sigf(sx * gB), m2, m3);

    // quad all-gather: value from quad-lane with gate q is arr[g^q]
    const float A1 = __shfl_xor(actA, 1);
    const float A2 = __shfl_xor(actA, 2);
    const float A3 = __shfl_xor(A1, 2);
    const float B1 = __shfl_xor(actB, 1);
    const float B2 = __shfl_xor(actB, 2);
    const float B3 = __shfl_xor(B1, 2);
    const float viA = sel4(actA, A1, A2, A3, g);
    const float vfA = sel4(actA, A1, A2, A3, g ^ 1);
    const float vgA = sel4(actA, A1, A2, A3, g ^ 2);
    const float voA = sel4(actA, A1, A2, A3, g ^ 3);
    const float viB = sel4(actB, B1, B2, B3, g);
    const float vfB = sel4(actB, B1, B2, B3, g ^ 1);
    const float vgB = sel4(actB, B1, B2, B3, g ^ 2);
    const float voB = sel4(actB, B1, B2, B3, g ^ 3);

    c0 = fmaf(vfA, c0, viA * vgA);                // redundant per quad
    c1 = fmaf(vfB, c1, viB * vgB);
    const float h0 = voA * fmaf(sigf(2.f * c0), 2.f, -1.f);
    const float h1 = voB * fmaf(sigf(2.f * c1), 2.f, -1.f);

    if (g == 0){
      _Float16* hn = hbuf + ((it + 1) & 1)*256;
      hn[jj]       = (_Float16)h0;
      hn[jj + 128] = (_Float16)h1;
      outcat[(size_t)t*512 + dir*256 + jj]       = h0;
      outcat[(size_t)t*512 + dir*256 + jj + 128] = h1;
    }
    __syncthreads();
  }
}

// ------------------------------ ab ------------------------------------------
__global__ __launch_bounds__(512) void ab_kernel(
    const float* __restrict__ outcat, const float* __restrict__ W1aT,
    const float* __restrict__ W1bT,  const float* __restrict__ b1,
    float* __restrict__ aP, float* __restrict__ bP)
{
  __shared__ float orow[512];
  const int tid = threadIdx.x;
  const int i = blockIdx.x;
  if (tid < 128) ((float4*)orow)[tid] = ((const float4*)(outcat + (size_t)i*512))[tid];
  __syncthreads();
  const int p = tid & 255, sel = tid >> 8;
  const float* W = sel ? W1bT : W1aT;
  float acc = sel ? 0.f : b1[p];
  #pragma unroll 8
  for (int cc = 0; cc < 512; ++cc) acc += orow[cc] * W[cc*256 + p];
  (sel ? bP : aP)[(size_t)i*256 + p] = acc;
}

// ------------------------------ fused MLP -----------------------------------
__global__ __launch_bounds__(256, 2) void mlp_kernel(
    const float* __restrict__ aP, const float* __restrict__ bP,
    const _Float16* __restrict__ W2h, const _Float16* __restrict__ W3h,
    const float* __restrict__ b2, const float* __restrict__ b3p,
    float* __restrict__ outp)
{
  __shared__ _Float16 lds[32768];   // 64KB union: W2 quarter (32KB) / h2 (64KB)
  const int tid = threadIdx.x;
  const int wv  = tid >> 6;
  const int ln  = tid & 31;
  const int hi  = (tid >> 5) & 1;
  const int i     = blockIdx.x >> 2;
  const int jbase = (blockIdx.x & 3) * 128;
  const int j     = jbase + wv*32 + ln;

  f32x16 acc[8];
  #pragma unroll
  for (int nt = 0; nt < 8; ++nt){
    #pragma unroll
    for (int e = 0; e < 16; ++e) acc[nt][e] = 0.f;
  }

  const float* arow = aP + (size_t)i*256;
  const float* brow = bP + (size_t)j*256;

  for (int p = 0; p < 4; ++p){
    if (p) __syncthreads();
    { // stage W2 quarter: rows n=tid, 64 k's, st_16x32 XOR swizzle
      const _Float16* src = W2h + tid*256 + p*64;
      char* dst = (char*)lds + tid*128;
      const int sw = (tid & 7) << 4;
      #pragma unroll
      for (int cc = 0; cc < 8; ++cc){
        f16x8 v = *(const f16x8*)(src + cc*8);
        *(f16x8*)(dst + ((cc*16) ^ sw)) = v;
      }
    }
    __syncthreads();
    #pragma unroll
    for (int ktl = 0; ktl < 4; ++ktl){
      const int kg = (p*4 + ktl)*16 + hi*8;
      float4 a0 = *(const float4*)(arow + kg);
      float4 a1 = *(const float4*)(arow + kg + 4);
      float4 b0 = *(const float4*)(brow + kg);
      float4 b1v = *(const float4*)(brow + kg + 4);
      f16x8 af;
      af[0] = (_Float16)fmaxf(a0.x + b0.x, 0.f);
      af[1] = (_Float16)fmaxf(a0.y + b0.y, 0.f);
      af[2] = (_Float16)fmaxf(a0.z + b0.z, 0.f);
      af[3] = (_Float16)fmaxf(a0.w + b0.w, 0.f);
      af[4] = (_Float16)fmaxf(a1.x + b1v.x, 0.f);
      af[5] = (_Float16)fmaxf(a1.y + b1v.y, 0.f);
      af[6] = (_Float16)fmaxf(a1.z + b1v.z, 0.f);
      af[7] = (_Float16)fmaxf(a1.w + b1v.w, 0.f);
      const int kl2 = (ktl*16 + hi*8) * 2;
      #pragma unroll
      for (int nt = 0; nt < 8; ++nt){
        const int n = nt*32 + ln;
        f16x8 bf = *(const f16x8*)((char*)lds + n*128 + (kl2 ^ ((n & 7) << 4)));
        acc[nt] = __builtin_amdgcn_mfma_f32_32x32x16_f16(af, bf, acc[nt], 0, 0, 0);
      }
    }
  }
  __syncthreads();
  // h2 -> LDS [128 pairs][256 ch] f16, XOR-swizzled per pair-row
  #pragma unroll
  for (int nt = 0; nt < 8; ++nt){
    const int ch = nt*32 + ln;
    const float bb = b2[ch];
    #pragma unroll
    for (int r = 0; r < 16; ++r){
      const int pr = wv*32 + (r & 3) + 8*(r >> 2) + 4*hi;
      const float v = fmaxf(acc[nt][r] + bb, 0.f);
      *(_Float16*)((char*)lds + pr*512 + ((ch*2) ^ ((pr & 7) << 4))) = (_Float16)v;
    }
  }
  __syncthreads();
  // logits
  f32x16 acc2[2];
  #pragma unroll
  for (int nt = 0; nt < 2; ++nt){
    #pragma unroll
    for (int e = 0; e < 16; ++e) acc2[nt][e] = 0.f;
  }
  const int pr = wv*32 + ln;
  const int sw2 = (pr & 7) << 4;
  #pragma unroll
  for (int kt = 0; kt < 16; ++kt){
    const int kb = kt*16 + hi*8;
    f16x8 a2 = *(const f16x8*)((char*)lds + pr*512 + ((kb*2) ^ sw2));
    #pragma unroll
    for (int nt = 0; nt < 2; ++nt){
      const int n = nt*32 + ln;
      f16x8 bf = *(const f16x8*)(W3h + n*256 + kb);
      acc2[nt] = __builtin_amdgcn_mfma_f32_32x32x16_f16(a2, bf, acc2[nt], 0, 0, 0);
    }
  }
  // log_softmax over 50 classes
  const float b30 = b3p[ln], b31 = b3p[32 + ln];
  const bool ok2 = (ln < 18);
  #pragma unroll
  for (int qr = 0; qr < 16; ++qr){
    const int r = (qr & 3) + 8*(qr >> 2) + 4*hi;
    float v0 = acc2[0][qr] + b30;
    float v1 = acc2[1][qr] + b31;
    float m = ok2 ? fmaxf(v0, v1) : v0;
    #pragma unroll
    for (int d = 1; d < 32; d <<= 1) m = fmaxf(m, __shfl_xor(m, d));
    float s = __expf(v0 - m) + (ok2 ? __expf(v1 - m) : 0.f);
    #pragma unroll
    for (int d = 1; d < 32; d <<= 1) s += __shfl_xor(s, d);
    const float lse = m + __logf(s);
    const size_t base = ((size_t)(i*512 + jbase + wv*32 + r)) * 50;
    outp[base + ln] = v0 - lse;
    if (ok2) outp[base + 32 + ln] = v1 - lse;
  }
}

// ------------------------------ launch --------------------------------------
extern "C" void kernel_launch(void* const* d_in, const int* in_sizes, int n_in,
                              void* d_out, int out_size, void* d_ws, size_t ws_size,
                              hipStream_t stream)
{
  const float* x     = (const float*)d_in[0];
  const float* Wih_f = (const float*)d_in[1];
  const float* Whh_f = (const float*)d_in[2];
  const float* bih_f = (const float*)d_in[3];
  const float* bhh_f = (const float*)d_in[4];
  const float* Wih_b = (const float*)d_in[5];
  const float* Whh_b = (const float*)d_in[6];
  const float* bih_b = (const float*)d_in[7];
  const float* bhh_b = (const float*)d_in[8];
  const float* W1    = (const float*)d_in[9];
  const float* b1    = (const float*)d_in[10];
  const float* W2    = (const float*)d_in[11];
  const float* b2    = (const float*)d_in[12];
  const float* W3    = (const float*)d_in[13];
  const float* b3    = (const float*)d_in[14];

  char* ws = (char*)d_ws;
  float*    xb     = (float*)(ws + 0);            // 4,194,304
  float*    outcat = (float*)(ws + 4194304);      // 1,048,576
  float*    aP     = (float*)(ws + 5242880);      //   524,288
  float*    bP     = (float*)(ws + 5767168);      //   524,288
  float*    WihT   = (float*)(ws + 6291456);      // 2,457,600
  float*    W1aT   = (float*)(ws + 8749056);      //   524,288
  float*    W1bT   = (float*)(ws + 9273344);      //   524,288
  _Float16* W2h    = (_Float16*)(ws + 9797632);   //   131,072
  _Float16* W3h    = (_Float16*)(ws + 9928704);   //    32,768
  float*    b3p    = (float*)(ws + 9961472);      //       256

  if (ws_size < 9963808) return;   // leaves d_out poisoned -> clean failure

  // lstm needs 132,096 B of dynamic LDS (>64 KB static limit)
  (void)hipFuncSetAttribute((const void*)lstm_kernel,
                            hipFuncAttributeMaxDynamicSharedMemorySize, 132096);

  prep_kernel<<<3745, 256, 0, stream>>>(Wih_f, Wih_b, W1, W2, W3, b3,
                                        WihT, W1aT, W1bT, W2h, W3h, b3p);
  xb_kernel<<<256, 256, 0, stream>>>(x, WihT, bih_f, bhh_f, bih_b, bhh_b, xb);
  lstm_kernel<<<2, 512, 132096, stream>>>(Whh_f, Whh_b, xb, outcat);
  ab_kernel<<<512, 512, 0, stream>>>(outcat, W1aT, W1bT, b1, aP, bP);
  mlp_kernel<<<2048, 256, 0, stream>>>(aP, bP, W2h, W3h, b2, b3p, (float*)d_out);
}

// Round 10
// 1052.751 us; speedup vs baseline: 1.7876x; 1.2177x over previous
//
#include <hip/hip_runtime.h>
#include <hip/hip_bf16.h>
#include <hip/hip_fp16.h>

// ---------------------------------------------------------------------------
// BiLSTM (N=512, D_IN=300, H=256) + pairwise 3-layer MLP (4H->H->H->50)
// + log_softmax, on MI355X.
//
//   lstm (round-10): MFMA-based recurrence. Rows permuted row'=unit*4+gate.
//   Per direction-block (512 thr, 8 waves): wave owns 8 16-row tiles of
//   Whh' (M=1024). 6 tiles as 48 f16x8 register frags (AGPR-resident -- MFMA
//   reads AGPRs natively, ending the VALU/AGPR copy war of r3-r9), 2 tiles
//   fragment-packed in LDS (128 KB, linear b128 reads). B = h broadcast to
//   all 16 cols. D col 0 gives owner lanes one unit's 4 gates in 4 regs ->
//   ds_write_b128 to gl -> barrier -> 256 threads gate-math (xb' permuted,
//   coalesced) -> h to LDS double buffer -> barrier. 2 barriers/step but
//   the 256-dot/thread VALU chain is GONE (MfmaUtil>0 expected at last).
// ---------------------------------------------------------------------------

typedef _Float16 f16x2 __attribute__((ext_vector_type(2)));
typedef _Float16 f16x8 __attribute__((ext_vector_type(8)));
typedef float    f32x4  __attribute__((ext_vector_type(4)));
typedef float    f32x16 __attribute__((ext_vector_type(16)));

__device__ __forceinline__ float sigf(float x){ return 1.f/(1.f + __expf(-x)); }

// ------------------------------ prep ---------------------------------------
__global__ __launch_bounds__(256) void prep_kernel(
    const float* __restrict__ Wih_f, const float* __restrict__ Wih_b,
    const float* __restrict__ W1,    const float* __restrict__ W2,
    const float* __restrict__ W3,    const float* __restrict__ b3,
    float* __restrict__ WihT, float* __restrict__ W1aT, float* __restrict__ W1bT,
    _Float16* __restrict__ W2h, _Float16* __restrict__ W3h,
    float* __restrict__ b3p)
{
  int idx = blockIdx.x * 256 + threadIdx.x;
  if (idx < 614400){                     // WihT[d][c][r] = Wih_d[r][c]
    int d = idx / 307200, r2 = idx % 307200;
    int cc = r2 / 1024, rr = r2 % 1024;
    const float* src = d ? Wih_b : Wih_f;
    WihT[idx] = src[rr*300 + cc];
    return;
  }
  idx -= 614400;
  if (idx < 262144){                     // W1aT[c][p]=W1[p][c]; W1bT[c][p]=W1[p][512+c]
    int sel = idx / 131072, r2 = idx % 131072;
    int cc = r2 / 256, pp = r2 % 256;
    float v = W1[pp*1024 + sel*512 + cc];
    (sel ? W1bT : W1aT)[r2] = v;
    return;
  }
  idx -= 262144;
  if (idx < 65536){ W2h[idx] = (_Float16)W2[idx]; return; }
  idx -= 65536;
  if (idx < 16384){                      // W3h padded to [64][256]
    int n = idx >> 8, k = idx & 255;
    W3h[idx] = (n < 50) ? (_Float16)W3[n*256 + k] : (_Float16)0.f;
    return;
  }
  idx -= 16384;
  if (idx < 64){ b3p[idx] = (idx < 50) ? b3[idx] : 0.f; return; }
}

// ------------------------------ xb ------------------------------------------
// Writes PERMUTED layout: xb'[t][unit*4 + gate]  (float4 per unit, coalesced)
__global__ __launch_bounds__(256) void xb_kernel(
    const float* __restrict__ x, const float* __restrict__ WihT,
    const float* __restrict__ bih_f, const float* __restrict__ bhh_f,
    const float* __restrict__ bih_b, const float* __restrict__ bhh_b,
    float* __restrict__ xb)
{
  const int tid = threadIdx.x;
  const int dir = blockIdx.x >> 7;
  const int t0  = (blockIdx.x & 127) * 4;
  __shared__ float xs[4][304];
  #pragma unroll
  for (int tt = 0; tt < 4; ++tt)
    if (tid < 75) ((float4*)xs[tt])[tid] = ((const float4*)(x + (size_t)(t0+tt)*300))[tid];
  __syncthreads();
  const float* W = WihT + dir*307200;
  float acc[4][4];
  #pragma unroll
  for (int r = 0; r < 4; ++r){
    #pragma unroll
    for (int tt = 0; tt < 4; ++tt) acc[r][tt] = 0.f;
  }
  for (int c = 0; c < 300; ++c){
    float x0 = xs[0][c], x1 = xs[1][c], x2 = xs[2][c], x3 = xs[3][c];
    #pragma unroll
    for (int r = 0; r < 4; ++r){
      float wv = W[c*1024 + r*256 + tid];
      acc[r][0] += wv*x0; acc[r][1] += wv*x1; acc[r][2] += wv*x2; acc[r][3] += wv*x3;
    }
  }
  const float* bih = dir ? bih_b : bih_f;
  const float* bhh = dir ? bhh_b : bhh_f;
  float bias[4];
  #pragma unroll
  for (int r = 0; r < 4; ++r) bias[r] = bih[r*256 + tid] + bhh[r*256 + tid];
  float* xbd = xb + (size_t)dir*512*1024;
  #pragma unroll
  for (int tt = 0; tt < 4; ++tt){
    float4 v;
    v.x = acc[0][tt] + bias[0];
    v.y = acc[1][tt] + bias[1];
    v.z = acc[2][tt] + bias[2];
    v.w = acc[3][tt] + bias[3];
    *(float4*)(xbd + (size_t)(t0+tt)*1024 + tid*4) = v;
  }
}

// ------------------------------ lstm ----------------------------------------
#define MFMA16(A, B, C) __builtin_amdgcn_mfma_f32_16x16x32_f16((A), (B), (C), 0, 0, 0)

__global__ __launch_bounds__(512)
__attribute__((amdgpu_waves_per_eu(2, 2)))
void lstm_kernel(
    const float* __restrict__ Whh_f, const float* __restrict__ Whh_b,
    const float* __restrict__ xb, float* __restrict__ outcat)
{
  extern __shared__ char smem[];
  // [0,131072): A-frag LDS tiles (2 per wave, fragment-packed)
  // [131072,135168): gl  f32[1024]   (gate results, unit-major)
  // [135168,136192): hbuf f16[2][256]
  char*     wbase = smem;
  float*    gl    = (float*)(smem + 131072);
  _Float16* hbuf  = (_Float16*)(smem + 135168);

  const int tid = threadIdx.x;
  const int dir = blockIdx.x;
  const int w   = tid >> 6;
  const int l   = tid & 63;
  const int lg  = l >> 4;      // k-group (0..3)
  const int lr  = l & 15;      // row within tile
  const float* Whh = dir ? Whh_b : Whh_f;

  char* wl = wbase + w*16384 + l*16;      // this lane's A-frag slot base

  // ---- init: load + permute + cvt weights into frags
  // tile tt of wave w covers rows' [(w*8+tt)*16, +16) ; row'=unit*4+gate
  f16x8 wreg[48];                          // tiles 0..5 (192 regs, AGPR ok)
  #pragma unroll
  for (int tt = 0; tt < 8; ++tt){
    const int rowp = (w*8 + tt)*16 + lr;
    const int orow = (rowp & 3)*256 + (rowp >> 2);
    const float* src = Whh + (size_t)orow*256 + lg*8;
    #pragma unroll
    for (int c = 0; c < 8; ++c){
      float4 v0 = *(const float4*)(src + c*32);
      float4 v1 = *(const float4*)(src + c*32 + 4);
      f16x8 o;
      o[0]=(_Float16)v0.x; o[1]=(_Float16)v0.y; o[2]=(_Float16)v0.z; o[3]=(_Float16)v0.w;
      o[4]=(_Float16)v1.x; o[5]=(_Float16)v1.y; o[6]=(_Float16)v1.z; o[7]=(_Float16)v1.w;
      if (tt < 6) wreg[tt*8 + c] = o;
      else        *(f16x8*)(wl + ((tt - 6)*8 + c)*1024) = o;
    }
  }
  if (tid < 32) ((f16x8*)hbuf)[tid] = (f16x8)(_Float16)0.f;    // h_{-1} = 0
  __syncthreads();

  const float* xbd = xb + (size_t)dir*512*1024;
  float cst = 0.f;                         // c-state (threads < 256)

  for (int it = 0; it < 512; ++it){
    const int t = dir ? (511 - it) : it;
    float4 xb4;
    if (tid < 256) xb4 = *(const float4*)(xbd + (size_t)t*1024 + tid*4);

    // B fragments: h broadcast to all cols; lane slot j <- h[c*32 + lg*8 + j]
    const _Float16* hsrc = hbuf + (it & 1)*256 + lg*8;
    f16x8 hf[8];
    #pragma unroll
    for (int c = 0; c < 8; ++c) hf[c] = *(const f16x8*)(hsrc + c*32);

    const bool owner = (lr == 0);
    // tile pairs: (0,1) (2,3) reg-only; (4,6) (5,7) mix reg+LDS
    {
      f32x4 a0 = {0.f,0.f,0.f,0.f}, a1 = {0.f,0.f,0.f,0.f};
      #pragma unroll
      for (int c = 0; c < 8; ++c){
        a0 = MFMA16(wreg[0*8+c], hf[c], a0);
        a1 = MFMA16(wreg[1*8+c], hf[c], a1);
      }
      if (owner){
        *(f32x4*)(gl + ((w*8+0)*4 + lg)*4) = a0;
        *(f32x4*)(gl + ((w*8+1)*4 + lg)*4) = a1;
      }
    }
    {
      f32x4 a0 = {0.f,0.f,0.f,0.f}, a1 = {0.f,0.f,0.f,0.f};
      #pragma unroll
      for (int c = 0; c < 8; ++c){
        a0 = MFMA16(wreg[2*8+c], hf[c], a0);
        a1 = MFMA16(wreg[3*8+c], hf[c], a1);
      }
      if (owner){
        *(f32x4*)(gl + ((w*8+2)*4 + lg)*4) = a0;
        *(f32x4*)(gl + ((w*8+3)*4 + lg)*4) = a1;
      }
    }
    {
      f32x4 a0 = {0.f,0.f,0.f,0.f}, a1 = {0.f,0.f,0.f,0.f};
      #pragma unroll
      for (int c = 0; c < 8; ++c){
        f16x8 w6 = *(const f16x8*)(wl + (0*8 + c)*1024);
        a0 = MFMA16(wreg[4*8+c], hf[c], a0);
        a1 = MFMA16(w6, hf[c], a1);
      }
      if (owner){
        *(f32x4*)(gl + ((w*8+4)*4 + lg)*4) = a0;
        *(f32x4*)(gl + ((w*8+6)*4 + lg)*4) = a1;
      }
    }
    {
      f32x4 a0 = {0.f,0.f,0.f,0.f}, a1 = {0.f,0.f,0.f,0.f};
      #pragma unroll
      for (int c = 0; c < 8; ++c){
        f16x8 w7 = *(const f16x8*)(wl + (1*8 + c)*1024);
        a0 = MFMA16(wreg[5*8+c], hf[c], a0);
        a1 = MFMA16(w7, hf[c], a1);
      }
      if (owner){
        *(f32x4*)(gl + ((w*8+5)*4 + lg)*4) = a0;
        *(f32x4*)(gl + ((w*8+7)*4 + lg)*4) = a1;
      }
    }
    __syncthreads();                       // gl complete

    if (tid < 256){
      f32x4 g4 = *(const f32x4*)(gl + tid*4);
      const float gi = g4[0] + xb4.x;
      const float gf = g4[1] + xb4.y;
      const float gg = g4[2] + xb4.z;
      const float go = g4[3] + xb4.w;
      const float iv = sigf(gi);
      const float fv = sigf(gf);
      const float gv = fmaf(sigf(2.f*gg), 2.f, -1.f);    // tanh
      const float ov = sigf(go);
      cst = fmaf(fv, cst, iv*gv);
      const float h = ov * fmaf(sigf(2.f*cst), 2.f, -1.f);
      hbuf[((it + 1) & 1)*256 + tid] = (_Float16)h;
      outcat[(size_t)t*512 + dir*256 + tid] = h;
    }
    __syncthreads();                       // hbuf ready for next step
  }
}

// ------------------------------ ab ------------------------------------------
__global__ __launch_bounds__(512) void ab_kernel(
    const float* __restrict__ outcat, const float* __restrict__ W1aT,
    const float* __restrict__ W1bT,  const float* __restrict__ b1,
    float* __restrict__ aP, float* __restrict__ bP)
{
  __shared__ float orow[512];
  const int tid = threadIdx.x;
  const int i = blockIdx.x;
  if (tid < 128) ((float4*)orow)[tid] = ((const float4*)(outcat + (size_t)i*512))[tid];
  __syncthreads();
  const int p = tid & 255, sel = tid >> 8;
  const float* W = sel ? W1bT : W1aT;
  float acc = sel ? 0.f : b1[p];
  #pragma unroll 8
  for (int cc = 0; cc < 512; ++cc) acc += orow[cc] * W[cc*256 + p];
  (sel ? bP : aP)[(size_t)i*256 + p] = acc;
}

// ------------------------------ fused MLP -----------------------------------
__global__ __launch_bounds__(256, 2) void mlp_kernel(
    const float* __restrict__ aP, const float* __restrict__ bP,
    const _Float16* __restrict__ W2h, const _Float16* __restrict__ W3h,
    const float* __restrict__ b2, const float* __restrict__ b3p,
    float* __restrict__ outp)
{
  __shared__ _Float16 lds[32768];   // 64KB union: W2 quarter (32KB) / h2 (64KB)
  const int tid = threadIdx.x;
  const int wv  = tid >> 6;
  const int ln  = tid & 31;
  const int hi  = (tid >> 5) & 1;
  const int i     = blockIdx.x >> 2;
  const int jbase = (blockIdx.x & 3) * 128;
  const int j     = jbase + wv*32 + ln;

  f32x16 acc[8];
  #pragma unroll
  for (int nt = 0; nt < 8; ++nt){
    #pragma unroll
    for (int e = 0; e < 16; ++e) acc[nt][e] = 0.f;
  }

  const float* arow = aP + (size_t)i*256;
  const float* brow = bP + (size_t)j*256;

  for (int p = 0; p < 4; ++p){
    if (p) __syncthreads();
    { // stage W2 quarter: rows n=tid, 64 k's, st_16x32 XOR swizzle
      const _Float16* src = W2h + tid*256 + p*64;
      char* dst = (char*)lds + tid*128;
      const int sw = (tid & 7) << 4;
      #pragma unroll
      for (int cc = 0; cc < 8; ++cc){
        f16x8 v = *(const f16x8*)(src + cc*8);
        *(f16x8*)(dst + ((cc*16) ^ sw)) = v;
      }
    }
    __syncthreads();
    #pragma unroll
    for (int ktl = 0; ktl < 4; ++ktl){
      const int kg = (p*4 + ktl)*16 + hi*8;
      float4 a0 = *(const float4*)(arow + kg);
      float4 a1 = *(const float4*)(arow + kg + 4);
      float4 b0 = *(const float4*)(brow + kg);
      float4 b1v = *(const float4*)(brow + kg + 4);
      f16x8 af;
      af[0] = (_Float16)fmaxf(a0.x + b0.x, 0.f);
      af[1] = (_Float16)fmaxf(a0.y + b0.y, 0.f);
      af[2] = (_Float16)fmaxf(a0.z + b0.z, 0.f);
      af[3] = (_Float16)fmaxf(a0.w + b0.w, 0.f);
      af[4] = (_Float16)fmaxf(a1.x + b1v.x, 0.f);
      af[5] = (_Float16)fmaxf(a1.y + b1v.y, 0.f);
      af[6] = (_Float16)fmaxf(a1.z + b1v.z, 0.f);
      af[7] = (_Float16)fmaxf(a1.w + b1v.w, 0.f);
      const int kl2 = (ktl*16 + hi*8) * 2;
      #pragma unroll
      for (int nt = 0; nt < 8; ++nt){
        const int n = nt*32 + ln;
        f16x8 bf = *(const f16x8*)((char*)lds + n*128 + (kl2 ^ ((n & 7) << 4)));
        acc[nt] = __builtin_amdgcn_mfma_f32_32x32x16_f16(af, bf, acc[nt], 0, 0, 0);
      }
    }
  }
  __syncthreads();
  // h2 -> LDS [128 pairs][256 ch] f16, XOR-swizzled per pair-row
  #pragma unroll
  for (int nt = 0; nt < 8; ++nt){
    const int ch = nt*32 + ln;
    const float bb = b2[ch];
    #pragma unroll
    for (int r = 0; r < 16; ++r){
      const int pr = wv*32 + (r & 3) + 8*(r >> 2) + 4*hi;
      const float v = fmaxf(acc[nt][r] + bb, 0.f);
      *(_Float16*)((char*)lds + pr*512 + ((ch*2) ^ ((pr & 7) << 4))) = (_Float16)v;
    }
  }
  __syncthreads();
  // logits
  f32x16 acc2[2];
  #pragma unroll
  for (int nt = 0; nt < 2; ++nt){
    #pragma unroll
    for (int e = 0; e < 16; ++e) acc2[nt][e] = 0.f;
  }
  const int pr = wv*32 + ln;
  const int sw2 = (pr & 7) << 4;
  #pragma unroll
  for (int kt = 0; kt < 16; ++kt){
    const int kb = kt*16 + hi*8;
    f16x8 a2 = *(const f16x8*)((char*)lds + pr*512 + ((kb*2) ^ sw2));
    #pragma unroll
    for (int nt = 0; nt < 2; ++nt){
      const int n = nt*32 + ln;
      f16x8 bf = *(const f16x8*)(W3h + n*256 + kb);
      acc2[nt] = __builtin_amdgcn_mfma_f32_32x32x16_f16(a2, bf, acc2[nt], 0, 0, 0);
    }
  }
  // log_softmax over 50 classes
  const float b30 = b3p[ln], b31 = b3p[32 + ln];
  const bool ok2 = (ln < 18);
  #pragma unroll
  for (int qr = 0; qr < 16; ++qr){
    const int r = (qr & 3) + 8*(qr >> 2) + 4*hi;
    float v0 = acc2[0][qr] + b30;
    float v1 = acc2[1][qr] + b31;
    float m = ok2 ? fmaxf(v0, v1) : v0;
    #pragma unroll
    for (int d = 1; d < 32; d <<= 1) m = fmaxf(m, __shfl_xor(m, d));
    float s = __expf(v0 - m) + (ok2 ? __expf(v1 - m) : 0.f);
    #pragma unroll
    for (int d = 1; d < 32; d <<= 1) s += __shfl_xor(s, d);
    const float lse = m + __logf(s);
    const size_t base = ((size_t)(i*512 + jbase + wv*32 + r)) * 50;
    outp[base + ln] = v0 - lse;
    if (ok2) outp[base + 32 + ln] = v1 - lse;
  }
}

// ------------------------------ launch --------------------------------------
extern "C" void kernel_launch(void* const* d_in, const int* in_sizes, int n_in,
                              void* d_out, int out_size, void* d_ws, size_t ws_size,
                              hipStream_t stream)
{
  const float* x     = (const float*)d_in[0];
  const float* Wih_f = (const float*)d_in[1];
  const float* Whh_f = (const float*)d_in[2];
  const float* bih_f = (const float*)d_in[3];
  const float* bhh_f = (const float*)d_in[4];
  const float* Wih_b = (const float*)d_in[5];
  const float* Whh_b = (const float*)d_in[6];
  const float* bih_b = (const float*)d_in[7];
  const float* bhh_b = (const float*)d_in[8];
  const float* W1    = (const float*)d_in[9];
  const float* b1    = (const float*)d_in[10];
  const float* W2    = (const float*)d_in[11];
  const float* b2    = (const float*)d_in[12];
  const float* W3    = (const float*)d_in[13];
  const float* b3    = (const float*)d_in[14];

  char* ws = (char*)d_ws;
  float*    xb     = (float*)(ws + 0);            // 4,194,304
  float*    outcat = (float*)(ws + 4194304);      // 1,048,576
  float*    aP     = (float*)(ws + 5242880);      //   524,288
  float*    bP     = (float*)(ws + 5767168);      //   524,288
  float*    WihT   = (float*)(ws + 6291456);      // 2,457,600
  float*    W1aT   = (float*)(ws + 8749056);      //   524,288
  float*    W1bT   = (float*)(ws + 9273344);      //   524,288
  _Float16* W2h    = (_Float16*)(ws + 9797632);   //   131,072
  _Float16* W3h    = (_Float16*)(ws + 9928704);   //    32,768
  float*    b3p    = (float*)(ws + 9961472);      //       256

  if (ws_size < 9963808) return;   // leaves d_out poisoned -> clean failure

  // lstm needs 136,192 B of dynamic LDS (>64 KB static limit)
  (void)hipFuncSetAttribute((const void*)lstm_kernel,
                            hipFuncAttributeMaxDynamicSharedMemorySize, 136192);

  prep_kernel<<<3745, 256, 0, stream>>>(Wih_f, Wih_b, W1, W2, W3, b3,
                                        WihT, W1aT, W1bT, W2h, W3h, b3p);
  xb_kernel<<<256, 256, 0, stream>>>(x, WihT, bih_f, bhh_f, bih_b, bhh_b, xb);
  lstm_kernel<<<2, 512, 136192, stream>>>(Whh_f, Whh_b, xb, outcat);
  ab_kernel<<<512, 512, 0, stream>>>(outcat, W1aT, W1bT, b1, aP, bP);
  mlp_kernel<<<2048, 256, 0, stream>>>(aP, bP, W2h, W3h, b2, b3p, (float*)d_out);
}